// Round 11
// baseline (4349.358 us; speedup 1.0000x reference)
//
#include <hip/hip_runtime.h>
#include <hip/hip_bf16.h>

// ---------------------------------------------------------------------------
// GCN (3-layer) + encoder + rank_diff stats, all fp32.
// R11: megastats tridiag on ONE WAVE with the 128x128 matrix in registers
//      (lane owns rows l and l+64; 256 VGPR). Zero barriers / zero cross-wave
//      combine in the Householder loop; column extraction via symmetry (owner
//      lane dumps its ROW = needed column, static register indexing).
//      Bisection still uses all 512 threads. Rest identical to R10.
// ---------------------------------------------------------------------------

#define DIM 128

// DPP helpers
template <int CTRL>
__device__ __forceinline__ float dpp_add(float v) {
  int x = __builtin_amdgcn_update_dpp(0, __float_as_int(v), CTRL, 0xF, 0xF, true);
  return v + __int_as_float(x);
}

// full 64-lane sum, result broadcast via readlane(63)
__device__ __forceinline__ float wave_sum(float v) {
  v = dpp_add<0xB1>(v);
  v = dpp_add<0x4E>(v);
  v = dpp_add<0x124>(v);
  v = dpp_add<0x128>(v);
  v = dpp_add<0x142>(v);
  v = dpp_add<0x143>(v);
  return __int_as_float(__builtin_amdgcn_readlane(__float_as_int(v), 63));
}

// ------------------------------- graph setup -------------------------------

__global__ void k_deg(const int* __restrict__ dst, unsigned* __restrict__ deg, int E) {
  int e = blockIdx.x * 256 + threadIdx.x;
  if (e < E) atomicAdd(&deg[dst[e]], 1u);
}

__global__ __launch_bounds__(1024) void k_scan1(const unsigned* __restrict__ deg,
                                                unsigned* __restrict__ loc,
                                                unsigned* __restrict__ part, int n) {
  __shared__ unsigned wtot[16];
  int tid = threadIdx.x, lane = tid & 63, wid = tid >> 6;
  int i = blockIdx.x * 1024 + tid;
  unsigned v = (i < n) ? deg[i] : 0u;
  unsigned s = v;
  #pragma unroll
  for (int d = 1; d < 64; d <<= 1) {
    unsigned t = __shfl_up(s, d);
    if (lane >= d) s += t;
  }
  if (lane == 63) wtot[wid] = s;
  __syncthreads();
  if (tid == 0) {
    unsigned acc = 0;
    #pragma unroll
    for (int w = 0; w < 16; w++) { unsigned t = wtot[w]; wtot[w] = acc; acc += t; }
    part[blockIdx.x] = acc;
  }
  __syncthreads();
  if (i < n) loc[i] = wtot[wid] + (s - v);
}

__global__ void k_scan2(unsigned* part, int nb) {
  int tid = threadIdx.x;  // 64 threads, nb <= 64
  unsigned v = (tid < nb) ? part[tid] : 0u;
  unsigned s = v;
  #pragma unroll
  for (int d = 1; d < 64; d <<= 1) {
    unsigned t = __shfl_up(s, d);
    if (tid >= d) s += t;
  }
  if (tid < nb) part[tid] = s - v;
  if (tid == 63) part[nb] = s;
}

__global__ __launch_bounds__(1024) void k_scan3(const unsigned* __restrict__ deg,
                                                const unsigned* __restrict__ part,
                                                unsigned* __restrict__ rowptr,
                                                unsigned* __restrict__ loc_cursor,
                                                float* __restrict__ dinv, int n, int nb) {
  int i = blockIdx.x * 1024 + threadIdx.x;
  if (i < n) {
    unsigned v = loc_cursor[i] + part[blockIdx.x];
    rowptr[i] = v;
    loc_cursor[i] = v;
    unsigned d = deg[i];
    dinv[i] = d ? 1.0f / sqrtf((float)d) : 0.0f;
  }
  if (i == 0) rowptr[n] = part[nb];
}

__global__ void k_scatter(const int* __restrict__ src, const int* __restrict__ dst,
                          const float* __restrict__ dinv, unsigned* __restrict__ cursor,
                          int* __restrict__ srcs, float* __restrict__ nrm, int E) {
  int e = blockIdx.x * 256 + threadIdx.x;
  if (e >= E) return;
  int s = src[e], d = dst[e];
  unsigned pos = atomicAdd(&cursor[d], 1u);
  srcs[pos] = s;
  nrm[pos] = dinv[s] * dinv[d];
}

// ---------------- GEMM: out = A @ W.T (+bias), + folded extract -------------

__global__ __launch_bounds__(256, 2) void k_gemm(const float* __restrict__ A,
                                                 const float* __restrict__ W,
                                                 const float* __restrict__ bias,
                                                 float* __restrict__ out, int M,
                                                 const unsigned long long* __restrict__ packed,
                                                 float* __restrict__ hrow) {
  const int tid = threadIdx.x;
  if (packed != nullptr && blockIdx.x == gridDim.x - 1) {
    if (tid < 128) {
      unsigned long long pk = *packed;
      unsigned i = 0xFFFFFFFFu - (unsigned)(pk & 0xFFFFFFFFull);
      if (i >= (unsigned)M) i = 0;
      hrow[tid] = A[(size_t)i * 128 + tid];
    }
    return;
  }
  __shared__ float Hs[32][132];   // k-major: Hs[kk][row]
  __shared__ float Ws[32][132];   // k-major: Ws[kk][col]
  const int r0 = blockIdx.x * 128;
  const int tx = tid & 15, ty = tid >> 4;
  const bool full = (r0 + 128 <= M);

  float acc[8][8];
  #pragma unroll
  for (int i = 0; i < 8; i++)
    #pragma unroll
    for (int j = 0; j < 8; j++) acc[i][j] = 0.f;

  #pragma unroll 1
  for (int k0 = 0; k0 < 128; k0 += 32) {
    #pragma unroll
    for (int i = 0; i < 4; i++) {
      int f4 = i * 256 + tid;
      int row = f4 >> 3, kq = f4 & 7;
      int gr = r0 + row;
      float4 v = make_float4(0.f, 0.f, 0.f, 0.f);
      if (full || gr < M) v = *(const float4*)&A[(size_t)gr * 128 + k0 + kq * 4];
      Hs[kq * 4 + 0][row] = v.x; Hs[kq * 4 + 1][row] = v.y;
      Hs[kq * 4 + 2][row] = v.z; Hs[kq * 4 + 3][row] = v.w;
    }
    #pragma unroll
    for (int i = 0; i < 4; i++) {
      int f4 = i * 256 + tid;
      int col = f4 >> 3, kq = f4 & 7;
      float4 v = *(const float4*)&W[(size_t)col * 128 + k0 + kq * 4];
      Ws[kq * 4 + 0][col] = v.x; Ws[kq * 4 + 1][col] = v.y;
      Ws[kq * 4 + 2][col] = v.z; Ws[kq * 4 + 3][col] = v.w;
    }
    __syncthreads();
    #pragma unroll 8
    for (int kk = 0; kk < 32; kk++) {
      float4 a0 = *(const float4*)&Hs[kk][ty * 8];
      float4 a1 = *(const float4*)&Hs[kk][ty * 8 + 4];
      float4 b0 = *(const float4*)&Ws[kk][tx * 8];
      float4 b1 = *(const float4*)&Ws[kk][tx * 8 + 4];
      float a[8] = { a0.x, a0.y, a0.z, a0.w, a1.x, a1.y, a1.z, a1.w };
      float b[8] = { b0.x, b0.y, b0.z, b0.w, b1.x, b1.y, b1.z, b1.w };
      #pragma unroll
      for (int i = 0; i < 8; i++)
        #pragma unroll
        for (int j = 0; j < 8; j++) acc[i][j] += a[i] * b[j];
    }
    __syncthreads();
  }

  float bb[8] = {0.f,0.f,0.f,0.f,0.f,0.f,0.f,0.f};
  if (bias) {
    float4 v0 = *(const float4*)&bias[tx * 8];
    float4 v1 = *(const float4*)&bias[tx * 8 + 4];
    bb[0]=v0.x; bb[1]=v0.y; bb[2]=v0.z; bb[3]=v0.w;
    bb[4]=v1.x; bb[5]=v1.y; bb[6]=v1.z; bb[7]=v1.w;
  }
  #pragma unroll
  for (int i = 0; i < 8; i++) {
    int gr = r0 + ty * 8 + i;
    if (full || gr < M) {
      float4 o0 = make_float4(acc[i][0]+bb[0], acc[i][1]+bb[1], acc[i][2]+bb[2], acc[i][3]+bb[3]);
      float4 o1 = make_float4(acc[i][4]+bb[4], acc[i][5]+bb[5], acc[i][6]+bb[6], acc[i][7]+bb[7]);
      *(float4*)&out[(size_t)gr * 128 + tx * 8] = o0;
      *(float4*)&out[(size_t)gr * 128 + tx * 8 + 4] = o1;
    }
  }
}

// --------------------- aggregation: 2 nodes/wave, float4 --------------------

template <bool RELU>
__global__ __launch_bounds__(256) void k_agg(const float* __restrict__ tmp,
                                             const unsigned* __restrict__ rowptr,
                                             const int* __restrict__ srcs,
                                             const float* __restrict__ nrm,
                                             const float* __restrict__ bias,
                                             float* __restrict__ out, int N) {
  int tid = threadIdx.x;
  int wid = tid >> 6, lane = tid & 63;
  int half = lane >> 5;
  int c4 = (lane & 31) * 4;
  int n = blockIdx.x * 8 + wid * 2 + half;
  if (n >= N) return;
  unsigned e = rowptr[n], e1 = rowptr[n + 1];
  float ax = 0.f, ay = 0.f, az = 0.f, aw = 0.f;
  for (; e + 2 <= e1; e += 2) {
    int s0 = srcs[e], s1 = srcs[e + 1];
    float w0 = nrm[e], w1 = nrm[e + 1];
    float4 x0 = *(const float4*)&tmp[(size_t)s0 * 128 + c4];
    float4 x1 = *(const float4*)&tmp[(size_t)s1 * 128 + c4];
    ax += w0 * x0.x + w1 * x1.x;
    ay += w0 * x0.y + w1 * x1.y;
    az += w0 * x0.z + w1 * x1.z;
    aw += w0 * x0.w + w1 * x1.w;
  }
  if (e < e1) {
    int s = srcs[e];
    float w = nrm[e];
    float4 x0 = *(const float4*)&tmp[(size_t)s * 128 + c4];
    ax += w * x0.x; ay += w * x0.y; az += w * x0.z; aw += w * x0.w;
  }
  float4 bv = *(const float4*)&bias[c4];
  ax += bv.x; ay += bv.y; az += bv.z; aw += bv.w;
  if (RELU) {
    ax = fmaxf(ax, 0.f); ay = fmaxf(ay, 0.f);
    az = fmaxf(az, 0.f); aw = fmaxf(aw, 0.f);
  }
  float4 o = make_float4(ax, ay, az, aw);
  *(float4*)&out[(size_t)n * 128 + c4] = o;
}

// --------------------- SYRK + row/col stats fused (R6) ---------------------

__global__ __launch_bounds__(256) void k_syrkstats(const float* __restrict__ h,
                                                   float* __restrict__ G,
                                                   float* __restrict__ colsum,
                                                   unsigned long long* __restrict__ packed,
                                                   int N, int rowsPer) {
  __shared__ float hs[8][132];
  __shared__ float csS[128];
  __shared__ unsigned long long pkS[8];
  int tid = threadIdx.x;
  int tx = tid & 15, ty = tid >> 4;
  int rr = tid >> 5, c4 = (tid & 31) * 4;
  float acc[8][8];
  #pragma unroll
  for (int i = 0; i < 8; i++)
    #pragma unroll
    for (int j = 0; j < 8; j++) acc[i][j] = 0.f;
  float ca0 = 0.f, ca1 = 0.f, ca2 = 0.f, ca3 = 0.f;
  unsigned long long best = 0;
  if (tid < 128) csS[tid] = 0.f;
  __syncthreads();

  int rstart = blockIdx.x * rowsPer;
  int rend = rstart + rowsPer;
  if (rend > N) rend = N;
  for (int rb = rstart; rb < rend; rb += 8) {
    int gr = rb + rr;
    float4 v = make_float4(0.f, 0.f, 0.f, 0.f);
    if (gr < rend) v = *(const float4*)&h[(size_t)gr * 128 + c4];
    __syncthreads();
    *(float4*)&hs[rr][c4] = v;
    float avx = fabsf(v.x), avy = fabsf(v.y), avz = fabsf(v.z), avw = fabsf(v.w);
    ca0 += avx; ca1 += avy; ca2 += avz; ca3 += avw;
    float rs = (avx + avy) + (avz + avw);
    rs = dpp_add<0xB1>(rs);
    rs = dpp_add<0x4E>(rs);
    rs = dpp_add<0x124>(rs);
    rs = dpp_add<0x128>(rs);
    rs = dpp_add<0x142>(rs);  // lanes 16-31 / 48-63 hold full 32-lane row sums
    if (gr < rend) {
      unsigned long long pk = ((unsigned long long)__float_as_uint(rs) << 32)
                            | (unsigned long long)(0xFFFFFFFFu - (unsigned)gr);
      if (pk > best) best = pk;
    }
    __syncthreads();
    #pragma unroll
    for (int r2 = 0; r2 < 8; r2++) {
      float4 a0 = *(const float4*)&hs[r2][ty * 8];
      float4 a1 = *(const float4*)&hs[r2][ty * 8 + 4];
      float4 b0 = *(const float4*)&hs[r2][tx * 8];
      float4 b1 = *(const float4*)&hs[r2][tx * 8 + 4];
      float a[8] = { a0.x,a0.y,a0.z,a0.w,a1.x,a1.y,a1.z,a1.w };
      float b[8] = { b0.x,b0.y,b0.z,b0.w,b1.x,b1.y,b1.z,b1.w };
      #pragma unroll
      for (int i = 0; i < 8; i++)
        #pragma unroll
        for (int j = 0; j < 8; j++) acc[i][j] += a[i] * b[j];
    }
  }
  if ((tid & 31) == 16) pkS[tid >> 5] = best;
  atomicAdd(&csS[c4 + 0], ca0);
  atomicAdd(&csS[c4 + 1], ca1);
  atomicAdd(&csS[c4 + 2], ca2);
  atomicAdd(&csS[c4 + 3], ca3);
  __syncthreads();
  if (tid == 0) {
    unsigned long long m = pkS[0];
    #pragma unroll
    for (int w = 1; w < 8; w++) if (pkS[w] > m) m = pkS[w];
    atomicMax(packed, m);
  }
  if (tid < 128) atomicAdd(&colsum[tid], csS[tid]);
  #pragma unroll
  for (int i = 0; i < 8; i++)
    #pragma unroll
    for (int j = 0; j < 8; j++)
      atomicAdd(&G[(size_t)(ty * 8 + i) * 128 + tx * 8 + j], acc[i][j]);
}

// ------------------------- megastats: 1-wave tridiag -----------------------
// One block per stat. Wave 0 holds A in registers (lane owns rows lane and
// lane+64) and runs the whole Householder tridiagonalization with NO barriers:
// reductions via DPP wave_sum, v/q staged through LDS broadcasts, column k+1
// extracted by symmetry (owner lane dumps its row, static reg indexing).
// Then all 512 threads run multisection bisection + trace-sqrt.

__global__ __launch_bounds__(512, 1) void k_megastats7(const float* __restrict__ Gall,
                                                       const float* __restrict__ colall,
                                                       const float* __restrict__ hrowall,
                                                       const unsigned long long* __restrict__ pkd3,
                                                       const float* __restrict__ h3, int N,
                                                       float* __restrict__ outstats) {
  const int blk = blockIdx.x;
  const float* G = Gall + (size_t)blk * 16384;
  const float* colsum = colall + blk * 128;

  __shared__ __align__(16) float colk[128];
  __shared__ __align__(16) float vS[128];
  __shared__ __align__(16) float qS[128];
  __shared__ float diag[128], offd[128];
  __shared__ float asS[128], b2S[128];
  __shared__ float loS[128], hiS[128];
  __shared__ float hiRow[128], gjS[128];
  __shared__ int cntS[512];
  __shared__ float redw[8];
  __shared__ float scal[16];
  __shared__ int ishared[4];

  const int tid = threadIdx.x;
  const int lane = tid & 63;
  const int wv = tid >> 6;     // wave 0..7
  const int r0 = lane;         // wave0: first owned row
  const int r1 = lane + 64;    // wave0: second owned row

  float A0[128], A1[128];      // only wave 0 uses these

  if (wv == 0) {
    #pragma unroll
    for (int c = 0; c < 128; c++) {
      A0[c] = 0.5f * (G[(size_t)r0 * 128 + c] + G[(size_t)c * 128 + r0]);
      A1[c] = 0.5f * (G[(size_t)r1 * 128 + c] + G[(size_t)c * 128 + r1]);
    }
  }

  for (int solve = 0; solve < 2; solve++) {
    if (wv == 0) {
      // init: colk = column 0 (each lane writes its own rows' entry; static idx)
      colk[r0] = A0[0];
      colk[r1] = A1[0];
      const float4* v4p = (const float4*)vS;
      const float4* q4p = (const float4*)qS;
      float4* ck4 = (float4*)colk;

      for (int k = 0; k <= 125; k++) {
        const int kp1 = k + 1;
        // read current column entries (own rows + scalars via broadcast)
        float ck0 = colk[r0], ck1 = colk[r1];
        float xk1 = colk[kp1];
        float dk = colk[k];
        float s2 = ((r0 > k) ? ck0 * ck0 : 0.f) + ((r1 > k) ? ck1 * ck1 : 0.f);
        float sig = wave_sum(s2);
        float nx = sqrtf(sig);
        float alpha = (xk1 >= 0.f) ? -nx : nx;
        float vns = 2.0f * (sig - alpha * xk1);
        float rvn = (vns > 1e-35f) ? rsqrtf(vns) : 0.f;
        float narvn = -alpha * rvn;
        if (lane == 0) { diag[k] = dk; offd[k] = alpha; }
        float v0 = (r0 <= k) ? 0.f : (ck0 * rvn + ((r0 == kp1) ? narvn : 0.f));
        float v1 = (r1 <= k) ? 0.f : (ck1 * rvn + ((r1 == kp1) ? narvn : 0.f));
        vS[r0] = v0;
        vS[r1] = v1;

        // matvec p = A v  (vS broadcast reads; 4-way split accumulators)
        float p0a = 0.f, p0b = 0.f, p0c = 0.f, p0d = 0.f;
        float p1a = 0.f, p1b = 0.f, p1c = 0.f, p1d = 0.f;
        #pragma unroll
        for (int i = 0; i < 32; i++) {
          float4 vv = v4p[i];
          p0a += A0[4*i+0] * vv.x; p0b += A0[4*i+1] * vv.y;
          p0c += A0[4*i+2] * vv.z; p0d += A0[4*i+3] * vv.w;
          p1a += A1[4*i+0] * vv.x; p1b += A1[4*i+1] * vv.y;
          p1c += A1[4*i+2] * vv.z; p1d += A1[4*i+3] * vv.w;
        }
        float p0 = (p0a + p0b) + (p0c + p0d);
        float p1 = (p1a + p1b) + (p1c + p1d);
        float lam = wave_sum(v0 * p0 + v1 * p1);
        float q0 = 2.0f * (p0 - lam * v0);
        float q1 = 2.0f * (p1 - lam * v1);
        qS[r0] = q0;
        qS[r1] = q1;

        // rank-2 update: A -= v q^T + q v^T
        #pragma unroll
        for (int i = 0; i < 32; i++) {
          float4 vv = v4p[i];
          float4 qq = q4p[i];
          A0[4*i+0] -= v0 * qq.x + q0 * vv.x;
          A0[4*i+1] -= v0 * qq.y + q0 * vv.y;
          A0[4*i+2] -= v0 * qq.z + q0 * vv.z;
          A0[4*i+3] -= v0 * qq.w + q0 * vv.w;
          A1[4*i+0] -= v1 * qq.x + q1 * vv.x;
          A1[4*i+1] -= v1 * qq.y + q1 * vv.y;
          A1[4*i+2] -= v1 * qq.z + q1 * vv.z;
          A1[4*i+3] -= v1 * qq.w + q1 * vv.w;
        }
        // dump column kp1 = row kp1 (symmetry); owner lane, static reg idx
        if (r0 == kp1) {
          #pragma unroll
          for (int i = 0; i < 32; i++)
            ck4[i] = make_float4(A0[4*i+0], A0[4*i+1], A0[4*i+2], A0[4*i+3]);
        }
        if (r1 == kp1) {
          #pragma unroll
          for (int i = 0; i < 32; i++)
            ck4[i] = make_float4(A1[4*i+0], A1[4*i+1], A1[4*i+2], A1[4*i+3]);
        }
      }
      // tail: colk now holds column 126
      if (lane == 0) { diag[126] = colk[126]; offd[126] = colk[127]; }
      if (lane == 63) diag[127] = A1[127];
    }
    __syncthreads();

    // ---- Gershgorin bound ----
    if (tid < 128) {
      float t = fabsf(diag[tid]);
      if (tid > 0) t += fabsf(offd[tid - 1]);
      if (tid < 127) t += fabsf(offd[tid]);
      #pragma unroll
      for (int m = 32; m >= 1; m >>= 1) t = fmaxf(t, __shfl_xor(t, m));
      if (lane == 0) redw[wv] = t;
    }
    __syncthreads();
    if (tid == 0) {
      float g = fmaxf(redw[0], redw[1]);
      if (!(g > 1e-30f)) g = 1.f;
      scal[3] = g; scal[5] = 1.0f / g;
    }
    __syncthreads();
    if (tid < 128) {
      float ginv = scal[5];
      asS[tid] = diag[tid] * ginv;
      float ob = (tid < 127) ? offd[tid] * ginv : 0.f;
      b2S[tid] = ob * ob;
      loS[tid] = -0.0625f;
      hiS[tid] = 1.03125f;
    }
    __syncthreads();

    // ---- multisection bisection (4 probes per eigenvalue, 12 rounds) ----
    for (int round = 0; round < 12; round++) {
      int kk = tid & 127;
      int t = tid >> 7;
      float l = loS[kk], h2v = hiS[kk];
      float sigma = l + (h2v - l) * 0.2f * (float)(t + 1);
      const float PIV = 1e-20f;
      float d = asS[0] - sigma;
      if (fabsf(d) < PIV) d = -PIV;
      int cnt = (d < 0.f) ? 1 : 0;
      for (int i = 1; i < 128; i++) {
        d = (asS[i] - sigma) - b2S[i - 1] * __builtin_amdgcn_rcpf(d);
        if (fabsf(d) < PIV) d = -PIV;
        cnt += (d < 0.f) ? 1 : 0;
      }
      cntS[tid] = cnt;
      __syncthreads();
      if (tid < 128) {
        int c0 = cntS[tid], c1 = cntS[tid + 128], c2 = cntS[tid + 256], c3 = cntS[tid + 384];
        float l2 = loS[tid], h2 = hiS[tid];
        float w = (h2 - l2) * 0.2f;
        int cross = 4;
        if (c0 > tid) cross = 0;
        else if (c1 > tid) cross = 1;
        else if (c2 > tid) cross = 2;
        else if (c3 > tid) cross = 3;
        loS[tid] = (cross == 0) ? l2 : l2 + w * (float)cross;
        hiS[tid] = (cross == 4) ? h2 : l2 + w * (float)(cross + 1);
      }
      __syncthreads();
    }
    // ---- sum sqrt eigenvalues ----
    if (tid < 128) {
      float lam2 = 0.5f * (loS[tid] + hiS[tid]);
      lam2 = fmaxf(lam2, 0.f) * scal[3];
      float s = sqrtf(lam2);
      #pragma unroll
      for (int m = 32; m >= 1; m >>= 1) s += __shfl_xor(s, m);
      if (lane == 0) redw[wv] = s;
    }
    __syncthreads();
    if (tid == 0) scal[4] = redw[0] + redw[1];
    __syncthreads();

    if (solve == 0) {
      // build second matrix G'
      if (tid < 128) {
        if (blk == 3) {
          unsigned long long pk = *pkd3;
          unsigned i = 0xFFFFFFFFu - (unsigned)(pk & 0xFFFFFFFFull);
          if (i >= (unsigned)N) i = 0;
          hiRow[tid] = h3[(size_t)i * 128 + tid];
        } else {
          hiRow[tid] = hrowall[blk * 128 + tid];
        }
      }
      __syncthreads();
      if (tid < 128) {
        float v = colsum[tid];
        int idx = tid;
        #pragma unroll
        for (int m = 32; m >= 1; m >>= 1) {
          float v2 = __shfl_xor(v, m);
          int i2 = __shfl_xor(idx, m);
          if (v2 > v || (v2 == v && i2 < idx)) { v = v2; idx = i2; }
        }
        if (lane == 0) { redw[wv] = v; ishared[wv] = idx; }
        float hv = hiRow[tid];
        float nh = hv * hv;
        #pragma unroll
        for (int m = 32; m >= 1; m >>= 1) nh += __shfl_xor(nh, m);
        if (lane == 0) redw[4 + wv] = nh;
      }
      __syncthreads();
      if (tid == 0) {
        float v0 = redw[0], v1 = redw[1];
        int j = (v1 > v0 || (v1 == v0 && ishared[1] < ishared[0])) ? ishared[1] : ishared[0];
        float nh2 = redw[4] + redw[5];
        float nu = scal[4];
        float Gjj = G[(size_t)j * 128 + j];
        float hij = hiRow[j];
        float sflip = (hij < 0.f) ? -1.f : 1.f;
        scal[6] = 1.0f / (nu * nu);
        scal[7] = sflip / (nu * sqrtf(Gjj) * sqrtf(nh2));
        scal[8] = 1.0f / nh2;
        ishared[2] = j;
      }
      __syncthreads();
      int j = ishared[2];
      if (tid < 128) gjS[tid] = 0.5f * (G[(size_t)tid * 128 + j] + G[(size_t)j * 128 + tid]);
      __syncthreads();
      if (wv == 0) {
        float inv2 = scal[6], c1 = scal[7], c2 = scal[8];
        float g0 = gjS[r0], h0 = hiRow[r0];
        float g1 = gjS[r1], h1 = hiRow[r1];
        #pragma unroll
        for (int c = 0; c < 128; c++) {
          float gs0 = 0.5f * (G[(size_t)r0 * 128 + c] + G[(size_t)c * 128 + r0]);
          float gs1 = 0.5f * (G[(size_t)r1 * 128 + c] + G[(size_t)c * 128 + r1]);
          float gc = gjS[c], hc = hiRow[c];
          A0[c] = gs0 * inv2 - c1 * (g0 * hc + h0 * gc) + c2 * h0 * hc;
          A1[c] = gs1 * inv2 - c1 * (g1 * hc + h1 * gc) + c2 * h1 * hc;
        }
      }
      __syncthreads();
    }
  }
  if (tid == 0) outstats[blk] = scal[4];
}

// ------------------------------- host driver -------------------------------

extern "C" void kernel_launch(void* const* d_in, const int* in_sizes, int n_in,
                              void* d_out, int out_size, void* d_ws, size_t ws_size,
                              hipStream_t stream) {
  const float* x = (const float*)d_in[0];
  const int* edge = (const int*)d_in[1];
  const float* encW = (const float*)d_in[2];
  const float* encb = (const float*)d_in[3];
  const float* W0 = (const float*)d_in[4];
  const float* b0 = (const float*)d_in[5];
  const float* W1 = (const float*)d_in[6];
  const float* b1 = (const float*)d_in[7];
  const float* W2 = (const float*)d_in[8];
  const float* b2 = (const float*)d_in[9];

  const int N = in_sizes[0] / 128;
  const int E = in_sizes[1] / 2;
  const int* esrc = edge;
  const int* edst = edge + E;

  float* out = (float*)d_out;
  float* stats_out = out + (size_t)N * 128;

  char* ws = (char*)d_ws;
  size_t offTmp = 0;
  size_t offG = offTmp + (size_t)N * 128 * 4;
  size_t offCol = offG + 4 * 16384 * 4;
  size_t offPkd = offCol + 4 * 128 * 4;
  size_t offHrow = offPkd + 4 * 8;
  size_t offDeg = offHrow + 4 * 128 * 4;
  size_t offRp = offDeg + (size_t)N * 4;
  size_t offCur = offRp + (size_t)(N + 1) * 4;
  size_t offDinv = offCur + (size_t)N * 4;
  size_t offSrc = offDinv + (size_t)N * 4;
  size_t offNrm = offSrc + (size_t)E * 4;
  size_t offPart = offNrm + (size_t)E * 4;
  size_t total = offPart + 256;
  if (ws_size < total) return;

  float* tmp = (float*)(ws + offTmp);
  float* Gall = (float*)(ws + offG);
  float* colall = (float*)(ws + offCol);
  unsigned long long* pkdall = (unsigned long long*)(ws + offPkd);
  float* hrowall = (float*)(ws + offHrow);
  unsigned* deg = (unsigned*)(ws + offDeg);
  unsigned* rowptr = (unsigned*)(ws + offRp);
  unsigned* cursor = (unsigned*)(ws + offCur);
  float* dinv = (float*)(ws + offDinv);
  int* srcs = (int*)(ws + offSrc);
  float* nrm = (float*)(ws + offNrm);
  unsigned* part = (unsigned*)(ws + offPart);

  hipMemsetAsync(ws + offG, 0, 4 * 16384 * 4 + 4 * 128 * 4 + 4 * 8, stream);
  hipMemsetAsync(ws + offDeg, 0, (size_t)N * 4, stream);

  const int EB = (E + 255) / 256;
  const int NB8 = (N + 7) / 8;
  const int GB = (N + 127) / 128;
  const int SB = (N + 1023) / 1024;
  const int SYB = 256;
  const int syrkRows = (N + SYB - 1) / SYB;

  k_deg<<<EB, 256, 0, stream>>>(edst, deg, E);
  k_scan1<<<SB, 1024, 0, stream>>>(deg, cursor, part, N);
  k_scan2<<<1, 64, 0, stream>>>(part, SB);
  k_scan3<<<SB, 1024, 0, stream>>>(deg, part, rowptr, cursor, dinv, N, SB);
  k_scatter<<<EB, 256, 0, stream>>>(esrc, edst, dinv, cursor, srcs, nrm, E);

  // encoder: h0 = x @ encW.T + encb  -> d_out
  k_gemm<<<GB, 256, 0, stream>>>(x, encW, encb, out, N, nullptr, nullptr);
  k_syrkstats<<<SYB, 256, 0, stream>>>(out, Gall + 0 * 16384, colall + 0 * 128, pkdall + 0, N, syrkRows);

  // layer 0 (gemm input = h0 -> folded extract for stat 0)
  k_gemm<<<GB + 1, 256, 0, stream>>>(out, W0, nullptr, tmp, N, pkdall + 0, hrowall + 0 * 128);
  k_agg<true><<<NB8, 256, 0, stream>>>(tmp, rowptr, srcs, nrm, b0, out, N);
  k_syrkstats<<<SYB, 256, 0, stream>>>(out, Gall + 1 * 16384, colall + 1 * 128, pkdall + 1, N, syrkRows);

  // layer 1 (gemm input = h1 -> folded extract for stat 1)
  k_gemm<<<GB + 1, 256, 0, stream>>>(out, W1, nullptr, tmp, N, pkdall + 1, hrowall + 1 * 128);
  k_agg<true><<<NB8, 256, 0, stream>>>(tmp, rowptr, srcs, nrm, b1, out, N);
  k_syrkstats<<<SYB, 256, 0, stream>>>(out, Gall + 2 * 16384, colall + 2 * 128, pkdall + 2, N, syrkRows);

  // layer 2 (gemm input = h2 -> folded extract for stat 2; no relu)
  k_gemm<<<GB + 1, 256, 0, stream>>>(out, W2, nullptr, tmp, N, pkdall + 2, hrowall + 2 * 128);
  k_agg<false><<<NB8, 256, 0, stream>>>(tmp, rowptr, srcs, nrm, b2, out, N);
  k_syrkstats<<<SYB, 256, 0, stream>>>(out, Gall + 3 * 16384, colall + 3 * 128, pkdall + 3, N, syrkRows);

  // all four stats concurrently (stat 3 self-extracts from out = h3)
  k_megastats7<<<4, 512, 0, stream>>>(Gall, colall, hrowall, pkdall + 3, out, N, stats_out);
}

// Round 12
// 1793.051 us; speedup vs baseline: 2.4257x; 2.4257x over previous
//
#include <hip/hip_runtime.h>
#include <hip/hip_bf16.h>

// ---------------------------------------------------------------------------
// GCN (3-layer) + encoder + rank_diff stats, all fp32.
// R12: consolidation. Mega = R6's proven 8-wave ds_add design (572us; the
//      empirical optimum of the 1/4/8/16-wave + reg-resident sweep; R11's
//      1-wave variant spilled to scratch). Chain = R10's improvements
//      (folded extracts, float4 agg) + 4-edge unrolled gather.
// ---------------------------------------------------------------------------

#define DIM 128

// DPP helpers
template <int CTRL>
__device__ __forceinline__ float dpp_add(float v) {
  int x = __builtin_amdgcn_update_dpp(0, __float_as_int(v), CTRL, 0xF, 0xF, true);
  return v + __int_as_float(x);
}

// full 64-lane sum, result broadcast via readlane(63)
__device__ __forceinline__ float wave_sum(float v) {
  v = dpp_add<0xB1>(v);
  v = dpp_add<0x4E>(v);
  v = dpp_add<0x124>(v);
  v = dpp_add<0x128>(v);
  v = dpp_add<0x142>(v);
  v = dpp_add<0x143>(v);
  return __int_as_float(__builtin_amdgcn_readlane(__float_as_int(v), 63));
}

// ------------------------------- graph setup -------------------------------

__global__ void k_deg(const int* __restrict__ dst, unsigned* __restrict__ deg, int E) {
  int e = blockIdx.x * 256 + threadIdx.x;
  if (e < E) atomicAdd(&deg[dst[e]], 1u);
}

__global__ __launch_bounds__(1024) void k_scan1(const unsigned* __restrict__ deg,
                                                unsigned* __restrict__ loc,
                                                unsigned* __restrict__ part, int n) {
  __shared__ unsigned wtot[16];
  int tid = threadIdx.x, lane = tid & 63, wid = tid >> 6;
  int i = blockIdx.x * 1024 + tid;
  unsigned v = (i < n) ? deg[i] : 0u;
  unsigned s = v;
  #pragma unroll
  for (int d = 1; d < 64; d <<= 1) {
    unsigned t = __shfl_up(s, d);
    if (lane >= d) s += t;
  }
  if (lane == 63) wtot[wid] = s;
  __syncthreads();
  if (tid == 0) {
    unsigned acc = 0;
    #pragma unroll
    for (int w = 0; w < 16; w++) { unsigned t = wtot[w]; wtot[w] = acc; acc += t; }
    part[blockIdx.x] = acc;
  }
  __syncthreads();
  if (i < n) loc[i] = wtot[wid] + (s - v);
}

__global__ void k_scan2(unsigned* part, int nb) {
  int tid = threadIdx.x;  // 64 threads, nb <= 64
  unsigned v = (tid < nb) ? part[tid] : 0u;
  unsigned s = v;
  #pragma unroll
  for (int d = 1; d < 64; d <<= 1) {
    unsigned t = __shfl_up(s, d);
    if (tid >= d) s += t;
  }
  if (tid < nb) part[tid] = s - v;
  if (tid == 63) part[nb] = s;
}

__global__ __launch_bounds__(1024) void k_scan3(const unsigned* __restrict__ deg,
                                                const unsigned* __restrict__ part,
                                                unsigned* __restrict__ rowptr,
                                                unsigned* __restrict__ loc_cursor,
                                                float* __restrict__ dinv, int n, int nb) {
  int i = blockIdx.x * 1024 + threadIdx.x;
  if (i < n) {
    unsigned v = loc_cursor[i] + part[blockIdx.x];
    rowptr[i] = v;
    loc_cursor[i] = v;
    unsigned d = deg[i];
    dinv[i] = d ? 1.0f / sqrtf((float)d) : 0.0f;
  }
  if (i == 0) rowptr[n] = part[nb];
}

__global__ void k_scatter(const int* __restrict__ src, const int* __restrict__ dst,
                          const float* __restrict__ dinv, unsigned* __restrict__ cursor,
                          int* __restrict__ srcs, float* __restrict__ nrm, int E) {
  int e = blockIdx.x * 256 + threadIdx.x;
  if (e >= E) return;
  int s = src[e], d = dst[e];
  unsigned pos = atomicAdd(&cursor[d], 1u);
  srcs[pos] = s;
  nrm[pos] = dinv[s] * dinv[d];
}

// ---------------- GEMM: out = A @ W.T (+bias), + folded extract -------------

__global__ __launch_bounds__(256, 2) void k_gemm(const float* __restrict__ A,
                                                 const float* __restrict__ W,
                                                 const float* __restrict__ bias,
                                                 float* __restrict__ out, int M,
                                                 const unsigned long long* __restrict__ packed,
                                                 float* __restrict__ hrow) {
  const int tid = threadIdx.x;
  if (packed != nullptr && blockIdx.x == gridDim.x - 1) {
    if (tid < 128) {
      unsigned long long pk = *packed;
      unsigned i = 0xFFFFFFFFu - (unsigned)(pk & 0xFFFFFFFFull);
      if (i >= (unsigned)M) i = 0;
      hrow[tid] = A[(size_t)i * 128 + tid];
    }
    return;
  }
  __shared__ float Hs[32][132];   // k-major: Hs[kk][row]
  __shared__ float Ws[32][132];   // k-major: Ws[kk][col]
  const int r0 = blockIdx.x * 128;
  const int tx = tid & 15, ty = tid >> 4;
  const bool full = (r0 + 128 <= M);

  float acc[8][8];
  #pragma unroll
  for (int i = 0; i < 8; i++)
    #pragma unroll
    for (int j = 0; j < 8; j++) acc[i][j] = 0.f;

  #pragma unroll 1
  for (int k0 = 0; k0 < 128; k0 += 32) {
    #pragma unroll
    for (int i = 0; i < 4; i++) {
      int f4 = i * 256 + tid;
      int row = f4 >> 3, kq = f4 & 7;
      int gr = r0 + row;
      float4 v = make_float4(0.f, 0.f, 0.f, 0.f);
      if (full || gr < M) v = *(const float4*)&A[(size_t)gr * 128 + k0 + kq * 4];
      Hs[kq * 4 + 0][row] = v.x; Hs[kq * 4 + 1][row] = v.y;
      Hs[kq * 4 + 2][row] = v.z; Hs[kq * 4 + 3][row] = v.w;
    }
    #pragma unroll
    for (int i = 0; i < 4; i++) {
      int f4 = i * 256 + tid;
      int col = f4 >> 3, kq = f4 & 7;
      float4 v = *(const float4*)&W[(size_t)col * 128 + k0 + kq * 4];
      Ws[kq * 4 + 0][col] = v.x; Ws[kq * 4 + 1][col] = v.y;
      Ws[kq * 4 + 2][col] = v.z; Ws[kq * 4 + 3][col] = v.w;
    }
    __syncthreads();
    #pragma unroll 8
    for (int kk = 0; kk < 32; kk++) {
      float4 a0 = *(const float4*)&Hs[kk][ty * 8];
      float4 a1 = *(const float4*)&Hs[kk][ty * 8 + 4];
      float4 b0 = *(const float4*)&Ws[kk][tx * 8];
      float4 b1 = *(const float4*)&Ws[kk][tx * 8 + 4];
      float a[8] = { a0.x, a0.y, a0.z, a0.w, a1.x, a1.y, a1.z, a1.w };
      float b[8] = { b0.x, b0.y, b0.z, b0.w, b1.x, b1.y, b1.z, b1.w };
      #pragma unroll
      for (int i = 0; i < 8; i++)
        #pragma unroll
        for (int j = 0; j < 8; j++) acc[i][j] += a[i] * b[j];
    }
    __syncthreads();
  }

  float bb[8] = {0.f,0.f,0.f,0.f,0.f,0.f,0.f,0.f};
  if (bias) {
    float4 v0 = *(const float4*)&bias[tx * 8];
    float4 v1 = *(const float4*)&bias[tx * 8 + 4];
    bb[0]=v0.x; bb[1]=v0.y; bb[2]=v0.z; bb[3]=v0.w;
    bb[4]=v1.x; bb[5]=v1.y; bb[6]=v1.z; bb[7]=v1.w;
  }
  #pragma unroll
  for (int i = 0; i < 8; i++) {
    int gr = r0 + ty * 8 + i;
    if (full || gr < M) {
      float4 o0 = make_float4(acc[i][0]+bb[0], acc[i][1]+bb[1], acc[i][2]+bb[2], acc[i][3]+bb[3]);
      float4 o1 = make_float4(acc[i][4]+bb[4], acc[i][5]+bb[5], acc[i][6]+bb[6], acc[i][7]+bb[7]);
      *(float4*)&out[(size_t)gr * 128 + tx * 8] = o0;
      *(float4*)&out[(size_t)gr * 128 + tx * 8 + 4] = o1;
    }
  }
}

// ------------- aggregation: 2 nodes/wave, float4, 4-edge unroll -------------

template <bool RELU>
__global__ __launch_bounds__(256) void k_agg(const float* __restrict__ tmp,
                                             const unsigned* __restrict__ rowptr,
                                             const int* __restrict__ srcs,
                                             const float* __restrict__ nrm,
                                             const float* __restrict__ bias,
                                             float* __restrict__ out, int N) {
  int tid = threadIdx.x;
  int wid = tid >> 6, lane = tid & 63;
  int half = lane >> 5;
  int c4 = (lane & 31) * 4;
  int n = blockIdx.x * 8 + wid * 2 + half;
  if (n >= N) return;
  unsigned e = rowptr[n], e1 = rowptr[n + 1];
  float ax = 0.f, ay = 0.f, az = 0.f, aw = 0.f;
  for (; e + 4 <= e1; e += 4) {
    int s0 = srcs[e], s1 = srcs[e + 1], s2 = srcs[e + 2], s3 = srcs[e + 3];
    float w0 = nrm[e], w1 = nrm[e + 1], w2 = nrm[e + 2], w3 = nrm[e + 3];
    float4 x0 = *(const float4*)&tmp[(size_t)s0 * 128 + c4];
    float4 x1 = *(const float4*)&tmp[(size_t)s1 * 128 + c4];
    float4 x2 = *(const float4*)&tmp[(size_t)s2 * 128 + c4];
    float4 x3 = *(const float4*)&tmp[(size_t)s3 * 128 + c4];
    ax += w0 * x0.x + w1 * x1.x + w2 * x2.x + w3 * x3.x;
    ay += w0 * x0.y + w1 * x1.y + w2 * x2.y + w3 * x3.y;
    az += w0 * x0.z + w1 * x1.z + w2 * x2.z + w3 * x3.z;
    aw += w0 * x0.w + w1 * x1.w + w2 * x2.w + w3 * x3.w;
  }
  for (; e < e1; ++e) {
    int s = srcs[e];
    float w = nrm[e];
    float4 x0 = *(const float4*)&tmp[(size_t)s * 128 + c4];
    ax += w * x0.x; ay += w * x0.y; az += w * x0.z; aw += w * x0.w;
  }
  float4 bv = *(const float4*)&bias[c4];
  ax += bv.x; ay += bv.y; az += bv.z; aw += bv.w;
  if (RELU) {
    ax = fmaxf(ax, 0.f); ay = fmaxf(ay, 0.f);
    az = fmaxf(az, 0.f); aw = fmaxf(aw, 0.f);
  }
  float4 o = make_float4(ax, ay, az, aw);
  *(float4*)&out[(size_t)n * 128 + c4] = o;
}

// --------------------- SYRK + row/col stats fused (R6) ---------------------

__global__ __launch_bounds__(256) void k_syrkstats(const float* __restrict__ h,
                                                   float* __restrict__ G,
                                                   float* __restrict__ colsum,
                                                   unsigned long long* __restrict__ packed,
                                                   int N, int rowsPer) {
  __shared__ float hs[8][132];
  __shared__ float csS[128];
  __shared__ unsigned long long pkS[8];
  int tid = threadIdx.x;
  int tx = tid & 15, ty = tid >> 4;
  int rr = tid >> 5, c4 = (tid & 31) * 4;
  float acc[8][8];
  #pragma unroll
  for (int i = 0; i < 8; i++)
    #pragma unroll
    for (int j = 0; j < 8; j++) acc[i][j] = 0.f;
  float ca0 = 0.f, ca1 = 0.f, ca2 = 0.f, ca3 = 0.f;
  unsigned long long best = 0;
  if (tid < 128) csS[tid] = 0.f;
  __syncthreads();

  int rstart = blockIdx.x * rowsPer;
  int rend = rstart + rowsPer;
  if (rend > N) rend = N;
  for (int rb = rstart; rb < rend; rb += 8) {
    int gr = rb + rr;
    float4 v = make_float4(0.f, 0.f, 0.f, 0.f);
    if (gr < rend) v = *(const float4*)&h[(size_t)gr * 128 + c4];
    __syncthreads();
    *(float4*)&hs[rr][c4] = v;
    float avx = fabsf(v.x), avy = fabsf(v.y), avz = fabsf(v.z), avw = fabsf(v.w);
    ca0 += avx; ca1 += avy; ca2 += avz; ca3 += avw;
    float rs = (avx + avy) + (avz + avw);
    rs = dpp_add<0xB1>(rs);
    rs = dpp_add<0x4E>(rs);
    rs = dpp_add<0x124>(rs);
    rs = dpp_add<0x128>(rs);
    rs = dpp_add<0x142>(rs);  // lanes 16-31 / 48-63 hold full 32-lane row sums
    if (gr < rend) {
      unsigned long long pk = ((unsigned long long)__float_as_uint(rs) << 32)
                            | (unsigned long long)(0xFFFFFFFFu - (unsigned)gr);
      if (pk > best) best = pk;
    }
    __syncthreads();
    #pragma unroll
    for (int r2 = 0; r2 < 8; r2++) {
      float4 a0 = *(const float4*)&hs[r2][ty * 8];
      float4 a1 = *(const float4*)&hs[r2][ty * 8 + 4];
      float4 b0 = *(const float4*)&hs[r2][tx * 8];
      float4 b1 = *(const float4*)&hs[r2][tx * 8 + 4];
      float a[8] = { a0.x,a0.y,a0.z,a0.w,a1.x,a1.y,a1.z,a1.w };
      float b[8] = { b0.x,b0.y,b0.z,b0.w,b1.x,b1.y,b1.z,b1.w };
      #pragma unroll
      for (int i = 0; i < 8; i++)
        #pragma unroll
        for (int j = 0; j < 8; j++) acc[i][j] += a[i] * b[j];
    }
  }
  if ((tid & 31) == 16) pkS[tid >> 5] = best;
  atomicAdd(&csS[c4 + 0], ca0);
  atomicAdd(&csS[c4 + 1], ca1);
  atomicAdd(&csS[c4 + 2], ca2);
  atomicAdd(&csS[c4 + 3], ca3);
  __syncthreads();
  if (tid == 0) {
    unsigned long long m = pkS[0];
    #pragma unroll
    for (int w = 1; w < 8; w++) if (pkS[w] > m) m = pkS[w];
    atomicMax(packed, m);
  }
  if (tid < 128) atomicAdd(&colsum[tid], csS[tid]);
  #pragma unroll
  for (int i = 0; i < 8; i++)
    #pragma unroll
    for (int j = 0; j < 8; j++)
      atomicAdd(&G[(size_t)(ty * 8 + i) * 128 + tx * 8 + j], acc[i][j]);
}

// ------------------------------- megastats (R6 verbatim) -------------------
// One block per stat: 2x (tridiag + bisection) trace-sqrt on 128x128 Gram.
// q-major, 8 waves, 2 barriers/step, ds_add w-combine (the measured optimum).

__global__ __launch_bounds__(512) void k_megastats4(const float* __restrict__ Gall,
                                                    const float* __restrict__ colall,
                                                    const float* __restrict__ hrowall,
                                                    const unsigned long long* __restrict__ pkd3,
                                                    const float* __restrict__ h3, int N,
                                                    float* __restrict__ outstats) {
  const int blk = blockIdx.x;
  const float* G = Gall + (size_t)blk * 16384;
  const float* colsum = colall + blk * 128;

  __shared__ __align__(16) float colk[128];
  __shared__ __align__(16) float wwF[256];    // ww[2][128] double buffer
  __shared__ __align__(16) float lamp[8];
  __shared__ float sigp[2];
  __shared__ float diag[128], offd[128];
  __shared__ float asS[128], b2S[128];
  __shared__ float loS[128], hiS[128];
  __shared__ float hiRow[128], gjS[128];
  __shared__ int cntS[512];
  __shared__ float redw[8];
  __shared__ float scal[16];
  __shared__ int ishared[4];

  const int tid = threadIdx.x;
  const int lane = tid & 63;
  const int wv = tid >> 6;     // wave 0..7
  const int q = tid >> 7;      // slice 0..3 (wave-pair)
  const int r = tid & 127;     // row
  const int cbase = q * 32;
  float Areg[32];

  #pragma unroll
  for (int cc = 0; cc < 32; cc++) {
    int c = cbase + cc;
    Areg[cc] = 0.5f * (G[(size_t)r * 128 + c] + G[(size_t)c * 128 + r]);
  }

  for (int solve = 0; solve < 2; solve++) {
    if (q == 0) colk[r] = (r == 0) ? 0.f : Areg[0];
    if (tid == 0) diag[0] = Areg[0];
    if (tid < 256) wwF[tid] = 0.f;
    if (q == 0) {
      float m2 = (r >= 1) ? Areg[0] * Areg[0] : 0.f;
      float s = wave_sum(m2);
      if (lane == 0) sigp[wv] = s;   // wv = 0,1
    }
    __syncthreads();

    for (int k = 0; k <= 125; k++) {
      const int kp1 = k + 1;
      float* wwc = &wwF[(k & 1) * 128];
      float* wwn = &wwF[(1 - (k & 1)) * 128];
      // ---- phase A ----
      float sig = sigp[0] + sigp[1];
      float xk1 = colk[kp1];
      float nx = sqrtf(sig);
      float alpha = (xk1 >= 0.f) ? -nx : nx;
      float vns = 2.0f * (sig - alpha * xk1);
      float rvn = (vns > 1e-35f) ? rsqrtf(vns) : 0.f;
      float narvn = -alpha * rvn;
      float ckr = colk[r];
      float vr = ckr * rvn + ((r == kp1) ? narvn : 0.f);
      const bool act = (cbase + 31 >= k);
      float4 cv[8];
      float p = 0.f;
      if (act) {
        const float4* cp = (const float4*)&colk[cbase];  // broadcast reads
        #pragma unroll
        for (int i = 0; i < 8; i++) cv[i] = cp[i];
        if (r >= k) {
          #pragma unroll
          for (int i = 0; i < 8; i++)
            p += Areg[4*i+0]*cv[i].x + Areg[4*i+1]*cv[i].y
               + Areg[4*i+2]*cv[i].z + Areg[4*i+3]*cv[i].w;
          int kl = kp1 - cbase;
          float akp1 = 0.f;
          if (kl >= 0 && kl < 32) {
            #pragma unroll
            for (int i = 0; i < 32; i++) if (i == kl) akp1 = Areg[i];
          }
          p = rvn * p + narvn * akp1;
          atomicAdd(&wwc[r], p);      // ds_add_f32, cross-wave combine
        }
      }
      float lp = vr * p;
      float ls = wave_sum(lp);
      if (lane == 0) lamp[wv] = ls;
      if (tid == 0) offd[k] = alpha;
      __syncthreads();

      // ---- phase B ----
      float4 l0 = *(const float4*)&lamp[0];
      float4 l1 = *(const float4*)&lamp[4];
      float lam = ((l0.x + l0.y) + (l0.z + l0.w)) + ((l1.x + l1.y) + (l1.z + l1.w));
      const int qo = kp1 >> 5;
      float nextc = 0.f;
      if (act && r >= k) {
        float wr = wwc[r];
        float qr = 2.0f * (wr - lam * vr);
        const int kl = kp1 - cbase;
        const float4* wp = (const float4*)&wwc[cbase];   // broadcast reads
        #pragma unroll
        for (int i = 0; i < 8; i++) {
          const int c0 = 4 * i;
          float4 wc = wp[i];
          float v0 = cv[i].x * rvn + ((c0 + 0 == kl) ? narvn : 0.f);
          float v1 = cv[i].y * rvn + ((c0 + 1 == kl) ? narvn : 0.f);
          float v2 = cv[i].z * rvn + ((c0 + 2 == kl) ? narvn : 0.f);
          float v3 = cv[i].w * rvn + ((c0 + 3 == kl) ? narvn : 0.f);
          float q0 = 2.f * (wc.x - lam * v0);
          float q1 = 2.f * (wc.y - lam * v1);
          float q2 = 2.f * (wc.z - lam * v2);
          float q3 = 2.f * (wc.w - lam * v3);
          float a0 = Areg[c0+0] - (vr * q0 + qr * v0); Areg[c0+0] = a0;
          float a1 = Areg[c0+1] - (vr * q1 + qr * v1); Areg[c0+1] = a1;
          float a2 = Areg[c0+2] - (vr * q2 + qr * v2); Areg[c0+2] = a2;
          float a3 = Areg[c0+3] - (vr * q3 + qr * v3); Areg[c0+3] = a3;
          if (c0 + 0 == kl) nextc = a0;
          if (c0 + 1 == kl) nextc = a1;
          if (c0 + 2 == kl) nextc = a2;
          if (c0 + 3 == kl) nextc = a3;
        }
      }
      if (q == qo && r >= k) colk[r] = (r <= kp1) ? 0.f : nextc;
      if (q == qo && r == kp1) diag[kp1] = nextc;
      if (q == qo) {
        float m2 = (r > kp1 && r >= k) ? nextc * nextc : 0.f;
        float s = wave_sum(m2);
        if (lane == 0) sigp[wv & 1] = s;
      }
      if (q == 1) wwn[r] = 0.f;   // zero next buffer
      __syncthreads();
    }
    if (tid == 0) offd[126] = colk[127];
    if (q == 3 && r == 127) diag[127] = Areg[31];
    __syncthreads();

    // ---- Gershgorin bound ----
    if (tid < 128) {
      float t = fabsf(diag[tid]);
      if (tid > 0) t += fabsf(offd[tid - 1]);
      if (tid < 127) t += fabsf(offd[tid]);
      #pragma unroll
      for (int m = 32; m >= 1; m >>= 1) t = fmaxf(t, __shfl_xor(t, m));
      if (lane == 0) redw[wv] = t;
    }
    __syncthreads();
    if (tid == 0) {
      float g = fmaxf(redw[0], redw[1]);
      if (!(g > 1e-30f)) g = 1.f;
      scal[3] = g; scal[5] = 1.0f / g;
    }
    __syncthreads();
    if (tid < 128) {
      float ginv = scal[5];
      asS[tid] = diag[tid] * ginv;
      float ob = (tid < 127) ? offd[tid] * ginv : 0.f;
      b2S[tid] = ob * ob;
      loS[tid] = -0.0625f;
      hiS[tid] = 1.03125f;
    }
    __syncthreads();

    // ---- multisection bisection (4 probes per eigenvalue, 12 rounds) ----
    for (int round = 0; round < 12; round++) {
      int kk = tid & 127;
      int t = tid >> 7;
      float l = loS[kk], h2v = hiS[kk];
      float sigma = l + (h2v - l) * 0.2f * (float)(t + 1);
      const float PIV = 1e-20f;
      float d = asS[0] - sigma;
      if (fabsf(d) < PIV) d = -PIV;
      int cnt = (d < 0.f) ? 1 : 0;
      for (int i = 1; i < 128; i++) {
        d = (asS[i] - sigma) - b2S[i - 1] * __builtin_amdgcn_rcpf(d);
        if (fabsf(d) < PIV) d = -PIV;
        cnt += (d < 0.f) ? 1 : 0;
      }
      cntS[tid] = cnt;
      __syncthreads();
      if (tid < 128) {
        int c0 = cntS[tid], c1 = cntS[tid + 128], c2 = cntS[tid + 256], c3 = cntS[tid + 384];
        float l2 = loS[tid], h2 = hiS[tid];
        float w = (h2 - l2) * 0.2f;
        int cross = 4;
        if (c0 > tid) cross = 0;
        else if (c1 > tid) cross = 1;
        else if (c2 > tid) cross = 2;
        else if (c3 > tid) cross = 3;
        loS[tid] = (cross == 0) ? l2 : l2 + w * (float)cross;
        hiS[tid] = (cross == 4) ? h2 : l2 + w * (float)(cross + 1);
      }
      __syncthreads();
    }
    // ---- sum sqrt eigenvalues ----
    if (tid < 128) {
      float lam2 = 0.5f * (loS[tid] + hiS[tid]);
      lam2 = fmaxf(lam2, 0.f) * scal[3];
      float s = sqrtf(lam2);
      #pragma unroll
      for (int m = 32; m >= 1; m >>= 1) s += __shfl_xor(s, m);
      if (lane == 0) redw[wv] = s;
    }
    __syncthreads();
    if (tid == 0) scal[4] = redw[0] + redw[1];
    __syncthreads();

    if (solve == 0) {
      if (tid < 128) {
        if (blk == 3) {
          unsigned long long pk = *pkd3;
          unsigned i = 0xFFFFFFFFu - (unsigned)(pk & 0xFFFFFFFFull);
          if (i >= (unsigned)N) i = 0;
          hiRow[tid] = h3[(size_t)i * 128 + tid];
        } else {
          hiRow[tid] = hrowall[blk * 128 + tid];
        }
      }
      __syncthreads();
      if (tid < 128) {
        float v = colsum[tid];
        int idx = tid;
        #pragma unroll
        for (int m = 32; m >= 1; m >>= 1) {
          float v2 = __shfl_xor(v, m);
          int i2 = __shfl_xor(idx, m);
          if (v2 > v || (v2 == v && i2 < idx)) { v = v2; idx = i2; }
        }
        if (lane == 0) { redw[wv] = v; ishared[wv] = idx; }
        float hv = hiRow[tid];
        float nh = hv * hv;
        #pragma unroll
        for (int m = 32; m >= 1; m >>= 1) nh += __shfl_xor(nh, m);
        if (lane == 0) redw[4 + wv] = nh;
      }
      __syncthreads();
      if (tid == 0) {
        float v0 = redw[0], v1 = redw[1];
        int j = (v1 > v0 || (v1 == v0 && ishared[1] < ishared[0])) ? ishared[1] : ishared[0];
        float nh2 = redw[4] + redw[5];
        float nu = scal[4];
        float Gjj = G[(size_t)j * 128 + j];
        float hij = hiRow[j];
        float sflip = (hij < 0.f) ? -1.f : 1.f;
        scal[6] = 1.0f / (nu * nu);
        scal[7] = sflip / (nu * sqrtf(Gjj) * sqrtf(nh2));
        scal[8] = 1.0f / nh2;
        ishared[2] = j;
      }
      __syncthreads();
      int j = ishared[2];
      if (tid < 128) gjS[tid] = 0.5f * (G[(size_t)tid * 128 + j] + G[(size_t)j * 128 + tid]);
      __syncthreads();
      float inv2 = scal[6], c1 = scal[7], c2 = scal[8];
      float gr_ = gjS[r], hr_ = hiRow[r];
      #pragma unroll
      for (int cc = 0; cc < 32; cc++) {
        int c = cbase + cc;
        float gsym = 0.5f * (G[(size_t)r * 128 + c] + G[(size_t)c * 128 + r]);
        Areg[cc] = gsym * inv2 - c1 * (gr_ * hiRow[c] + hr_ * gjS[c]) + c2 * hr_ * hiRow[c];
      }
      __syncthreads();
    }
  }
  if (tid == 0) outstats[blk] = scal[4];
}

// ------------------------------- host driver -------------------------------

extern "C" void kernel_launch(void* const* d_in, const int* in_sizes, int n_in,
                              void* d_out, int out_size, void* d_ws, size_t ws_size,
                              hipStream_t stream) {
  const float* x = (const float*)d_in[0];
  const int* edge = (const int*)d_in[1];
  const float* encW = (const float*)d_in[2];
  const float* encb = (const float*)d_in[3];
  const float* W0 = (const float*)d_in[4];
  const float* b0 = (const float*)d_in[5];
  const float* W1 = (const float*)d_in[6];
  const float* b1 = (const float*)d_in[7];
  const float* W2 = (const float*)d_in[8];
  const float* b2 = (const float*)d_in[9];

  const int N = in_sizes[0] / 128;
  const int E = in_sizes[1] / 2;
  const int* esrc = edge;
  const int* edst = edge + E;

  float* out = (float*)d_out;
  float* stats_out = out + (size_t)N * 128;

  char* ws = (char*)d_ws;
  size_t offTmp = 0;
  size_t offG = offTmp + (size_t)N * 128 * 4;
  size_t offCol = offG + 4 * 16384 * 4;
  size_t offPkd = offCol + 4 * 128 * 4;
  size_t offHrow = offPkd + 4 * 8;
  size_t offDeg = offHrow + 4 * 128 * 4;
  size_t offRp = offDeg + (size_t)N * 4;
  size_t offCur = offRp + (size_t)(N + 1) * 4;
  size_t offDinv = offCur + (size_t)N * 4;
  size_t offSrc = offDinv + (size_t)N * 4;
  size_t offNrm = offSrc + (size_t)E * 4;
  size_t offPart = offNrm + (size_t)E * 4;
  size_t total = offPart + 256;
  if (ws_size < total) return;

  float* tmp = (float*)(ws + offTmp);
  float* Gall = (float*)(ws + offG);
  float* colall = (float*)(ws + offCol);
  unsigned long long* pkdall = (unsigned long long*)(ws + offPkd);
  float* hrowall = (float*)(ws + offHrow);
  unsigned* deg = (unsigned*)(ws + offDeg);
  unsigned* rowptr = (unsigned*)(ws + offRp);
  unsigned* cursor = (unsigned*)(ws + offCur);
  float* dinv = (float*)(ws + offDinv);
  int* srcs = (int*)(ws + offSrc);
  float* nrm = (float*)(ws + offNrm);
  unsigned* part = (unsigned*)(ws + offPart);

  hipMemsetAsync(ws + offG, 0, 4 * 16384 * 4 + 4 * 128 * 4 + 4 * 8, stream);
  hipMemsetAsync(ws + offDeg, 0, (size_t)N * 4, stream);

  const int EB = (E + 255) / 256;
  const int NB8 = (N + 7) / 8;
  const int GB = (N + 127) / 128;
  const int SB = (N + 1023) / 1024;
  const int SYB = 256;
  const int syrkRows = (N + SYB - 1) / SYB;

  k_deg<<<EB, 256, 0, stream>>>(edst, deg, E);
  k_scan1<<<SB, 1024, 0, stream>>>(deg, cursor, part, N);
  k_scan2<<<1, 64, 0, stream>>>(part, SB);
  k_scan3<<<SB, 1024, 0, stream>>>(deg, part, rowptr, cursor, dinv, N, SB);
  k_scatter<<<EB, 256, 0, stream>>>(esrc, edst, dinv, cursor, srcs, nrm, E);

  // encoder: h0 = x @ encW.T + encb  -> d_out
  k_gemm<<<GB, 256, 0, stream>>>(x, encW, encb, out, N, nullptr, nullptr);
  k_syrkstats<<<SYB, 256, 0, stream>>>(out, Gall + 0 * 16384, colall + 0 * 128, pkdall + 0, N, syrkRows);

  // layer 0 (gemm input = h0 -> folded extract for stat 0)
  k_gemm<<<GB + 1, 256, 0, stream>>>(out, W0, nullptr, tmp, N, pkdall + 0, hrowall + 0 * 128);
  k_agg<true><<<NB8, 256, 0, stream>>>(tmp, rowptr, srcs, nrm, b0, out, N);
  k_syrkstats<<<SYB, 256, 0, stream>>>(out, Gall + 1 * 16384, colall + 1 * 128, pkdall + 1, N, syrkRows);

  // layer 1 (gemm input = h1 -> folded extract for stat 1)
  k_gemm<<<GB + 1, 256, 0, stream>>>(out, W1, nullptr, tmp, N, pkdall + 1, hrowall + 1 * 128);
  k_agg<true><<<NB8, 256, 0, stream>>>(tmp, rowptr, srcs, nrm, b1, out, N);
  k_syrkstats<<<SYB, 256, 0, stream>>>(out, Gall + 2 * 16384, colall + 2 * 128, pkdall + 2, N, syrkRows);

  // layer 2 (gemm input = h2 -> folded extract for stat 2; no relu)
  k_gemm<<<GB + 1, 256, 0, stream>>>(out, W2, nullptr, tmp, N, pkdall + 2, hrowall + 2 * 128);
  k_agg<false><<<NB8, 256, 0, stream>>>(tmp, rowptr, srcs, nrm, b2, out, N);
  k_syrkstats<<<SYB, 256, 0, stream>>>(out, Gall + 3 * 16384, colall + 3 * 128, pkdall + 3, N, syrkRows);

  // all four stats concurrently (stat 3 self-extracts from out = h3)
  k_megastats4<<<4, 512, 0, stream>>>(Gall, colall, hrowall, pkdall + 3, out, N, stats_out);
}

// Round 13
// 1180.610 us; speedup vs baseline: 3.6840x; 1.5187x over previous
//
#include <hip/hip_runtime.h>
#include <hip/hip_bf16.h>

// ---------------------------------------------------------------------------
// GCN (3-layer) + encoder + rank_diff stats, all fp32.
// R13: de-atomic syrkstats G-accumulation. Each syrk block stores a private
//      64KB partial-G slice (no atomics); 64 reduce blocks folded into the
//      next gemm launch (standalone reduce for G3) sum the partials.
//      Everything else = R12 (mega = R6 8-wave optimum, 575us).
// ---------------------------------------------------------------------------

#define DIM 128
#define SYB 128   // syrk blocks == partial slices

// DPP helpers
template <int CTRL>
__device__ __forceinline__ float dpp_add(float v) {
  int x = __builtin_amdgcn_update_dpp(0, __float_as_int(v), CTRL, 0xF, 0xF, true);
  return v + __int_as_float(x);
}

// full 64-lane sum, result broadcast via readlane(63)
__device__ __forceinline__ float wave_sum(float v) {
  v = dpp_add<0xB1>(v);
  v = dpp_add<0x4E>(v);
  v = dpp_add<0x124>(v);
  v = dpp_add<0x128>(v);
  v = dpp_add<0x142>(v);
  v = dpp_add<0x143>(v);
  return __int_as_float(__builtin_amdgcn_readlane(__float_as_int(v), 63));
}

// ------------------------------- graph setup -------------------------------

__global__ void k_deg(const int* __restrict__ dst, unsigned* __restrict__ deg, int E) {
  int e = blockIdx.x * 256 + threadIdx.x;
  if (e < E) atomicAdd(&deg[dst[e]], 1u);
}

__global__ __launch_bounds__(1024) void k_scan1(const unsigned* __restrict__ deg,
                                                unsigned* __restrict__ loc,
                                                unsigned* __restrict__ part, int n) {
  __shared__ unsigned wtot[16];
  int tid = threadIdx.x, lane = tid & 63, wid = tid >> 6;
  int i = blockIdx.x * 1024 + tid;
  unsigned v = (i < n) ? deg[i] : 0u;
  unsigned s = v;
  #pragma unroll
  for (int d = 1; d < 64; d <<= 1) {
    unsigned t = __shfl_up(s, d);
    if (lane >= d) s += t;
  }
  if (lane == 63) wtot[wid] = s;
  __syncthreads();
  if (tid == 0) {
    unsigned acc = 0;
    #pragma unroll
    for (int w = 0; w < 16; w++) { unsigned t = wtot[w]; wtot[w] = acc; acc += t; }
    part[blockIdx.x] = acc;
  }
  __syncthreads();
  if (i < n) loc[i] = wtot[wid] + (s - v);
}

__global__ void k_scan2(unsigned* part, int nb) {
  int tid = threadIdx.x;  // 64 threads, nb <= 64
  unsigned v = (tid < nb) ? part[tid] : 0u;
  unsigned s = v;
  #pragma unroll
  for (int d = 1; d < 64; d <<= 1) {
    unsigned t = __shfl_up(s, d);
    if (tid >= d) s += t;
  }
  if (tid < nb) part[tid] = s - v;
  if (tid == 63) part[nb] = s;
}

__global__ __launch_bounds__(1024) void k_scan3(const unsigned* __restrict__ deg,
                                                const unsigned* __restrict__ part,
                                                unsigned* __restrict__ rowptr,
                                                unsigned* __restrict__ loc_cursor,
                                                float* __restrict__ dinv, int n, int nb) {
  int i = blockIdx.x * 1024 + threadIdx.x;
  if (i < n) {
    unsigned v = loc_cursor[i] + part[blockIdx.x];
    rowptr[i] = v;
    loc_cursor[i] = v;
    unsigned d = deg[i];
    dinv[i] = d ? 1.0f / sqrtf((float)d) : 0.0f;
  }
  if (i == 0) rowptr[n] = part[nb];
}

__global__ void k_scatter(const int* __restrict__ src, const int* __restrict__ dst,
                          const float* __restrict__ dinv, unsigned* __restrict__ cursor,
                          int* __restrict__ srcs, float* __restrict__ nrm, int E) {
  int e = blockIdx.x * 256 + threadIdx.x;
  if (e >= E) return;
  int s = src[e], d = dst[e];
  unsigned pos = atomicAdd(&cursor[d], 1u);
  srcs[pos] = s;
  nrm[pos] = dinv[s] * dinv[d];
}

// ------ GEMM: out = A @ W.T (+bias), + folded extract + folded G-reduce -----
// grid = GB [+ 1 extract block] [+ 64 reduce blocks].
// GB is computed in-kernel from M. Reduce blocks sum SYB partial-G slices.

__global__ __launch_bounds__(256, 2) void k_gemm(const float* __restrict__ A,
                                                 const float* __restrict__ W,
                                                 const float* __restrict__ bias,
                                                 float* __restrict__ out, int M,
                                                 const unsigned long long* __restrict__ packed,
                                                 float* __restrict__ hrow,
                                                 const float* __restrict__ Gp,
                                                 float* __restrict__ Gout) {
  const int tid = threadIdx.x;
  const int GBc = (M + 127) >> 7;
  const int bid = blockIdx.x;
  if (bid >= GBc) {
    if (bid == GBc) {
      if (packed != nullptr && tid < 128) {
        unsigned long long pk = *packed;
        unsigned i = 0xFFFFFFFFu - (unsigned)(pk & 0xFFFFFFFFull);
        if (i >= (unsigned)M) i = 0;
        hrow[tid] = A[(size_t)i * 128 + tid];
      }
    } else if (Gp != nullptr) {
      int idx = (bid - GBc - 1) * 256 + tid;   // 64 blocks x 256 = 16384
      float s = 0.f;
      #pragma unroll 8
      for (int p = 0; p < SYB; p++) s += Gp[(size_t)p * 16384 + idx];
      Gout[idx] = s;
    }
    return;
  }
  __shared__ float Hs[32][132];   // k-major: Hs[kk][row]
  __shared__ float Ws[32][132];   // k-major: Ws[kk][col]
  const int r0 = bid * 128;
  const int tx = tid & 15, ty = tid >> 4;
  const bool full = (r0 + 128 <= M);

  float acc[8][8];
  #pragma unroll
  for (int i = 0; i < 8; i++)
    #pragma unroll
    for (int j = 0; j < 8; j++) acc[i][j] = 0.f;

  #pragma unroll 1
  for (int k0 = 0; k0 < 128; k0 += 32) {
    #pragma unroll
    for (int i = 0; i < 4; i++) {
      int f4 = i * 256 + tid;
      int row = f4 >> 3, kq = f4 & 7;
      int gr = r0 + row;
      float4 v = make_float4(0.f, 0.f, 0.f, 0.f);
      if (full || gr < M) v = *(const float4*)&A[(size_t)gr * 128 + k0 + kq * 4];
      Hs[kq * 4 + 0][row] = v.x; Hs[kq * 4 + 1][row] = v.y;
      Hs[kq * 4 + 2][row] = v.z; Hs[kq * 4 + 3][row] = v.w;
    }
    #pragma unroll
    for (int i = 0; i < 4; i++) {
      int f4 = i * 256 + tid;
      int col = f4 >> 3, kq = f4 & 7;
      float4 v = *(const float4*)&W[(size_t)col * 128 + k0 + kq * 4];
      Ws[kq * 4 + 0][col] = v.x; Ws[kq * 4 + 1][col] = v.y;
      Ws[kq * 4 + 2][col] = v.z; Ws[kq * 4 + 3][col] = v.w;
    }
    __syncthreads();
    #pragma unroll 8
    for (int kk = 0; kk < 32; kk++) {
      float4 a0 = *(const float4*)&Hs[kk][ty * 8];
      float4 a1 = *(const float4*)&Hs[kk][ty * 8 + 4];
      float4 b0 = *(const float4*)&Ws[kk][tx * 8];
      float4 b1 = *(const float4*)&Ws[kk][tx * 8 + 4];
      float a[8] = { a0.x, a0.y, a0.z, a0.w, a1.x, a1.y, a1.z, a1.w };
      float b[8] = { b0.x, b0.y, b0.z, b0.w, b1.x, b1.y, b1.z, b1.w };
      #pragma unroll
      for (int i = 0; i < 8; i++)
        #pragma unroll
        for (int j = 0; j < 8; j++) acc[i][j] += a[i] * b[j];
    }
    __syncthreads();
  }

  float bb[8] = {0.f,0.f,0.f,0.f,0.f,0.f,0.f,0.f};
  if (bias) {
    float4 v0 = *(const float4*)&bias[tx * 8];
    float4 v1 = *(const float4*)&bias[tx * 8 + 4];
    bb[0]=v0.x; bb[1]=v0.y; bb[2]=v0.z; bb[3]=v0.w;
    bb[4]=v1.x; bb[5]=v1.y; bb[6]=v1.z; bb[7]=v1.w;
  }
  #pragma unroll
  for (int i = 0; i < 8; i++) {
    int gr = r0 + ty * 8 + i;
    if (full || gr < M) {
      float4 o0 = make_float4(acc[i][0]+bb[0], acc[i][1]+bb[1], acc[i][2]+bb[2], acc[i][3]+bb[3]);
      float4 o1 = make_float4(acc[i][4]+bb[4], acc[i][5]+bb[5], acc[i][6]+bb[6], acc[i][7]+bb[7]);
      *(float4*)&out[(size_t)gr * 128 + tx * 8] = o0;
      *(float4*)&out[(size_t)gr * 128 + tx * 8 + 4] = o1;
    }
  }
}

// standalone G-reduce (for the last layer's G, before megastats)
__global__ void k_greduce(const float* __restrict__ Gp, float* __restrict__ Gout) {
  int idx = blockIdx.x * 256 + threadIdx.x;
  float s = 0.f;
  #pragma unroll 8
  for (int p = 0; p < SYB; p++) s += Gp[(size_t)p * 16384 + idx];
  Gout[idx] = s;
}

// ------------- aggregation: 2 nodes/wave, float4, 4-edge unroll -------------

template <bool RELU>
__global__ __launch_bounds__(256) void k_agg(const float* __restrict__ tmp,
                                             const unsigned* __restrict__ rowptr,
                                             const int* __restrict__ srcs,
                                             const float* __restrict__ nrm,
                                             const float* __restrict__ bias,
                                             float* __restrict__ out, int N) {
  int tid = threadIdx.x;
  int wid = tid >> 6, lane = tid & 63;
  int half = lane >> 5;
  int c4 = (lane & 31) * 4;
  int n = blockIdx.x * 8 + wid * 2 + half;
  if (n >= N) return;
  unsigned e = rowptr[n], e1 = rowptr[n + 1];
  float ax = 0.f, ay = 0.f, az = 0.f, aw = 0.f;
  for (; e + 4 <= e1; e += 4) {
    int s0 = srcs[e], s1 = srcs[e + 1], s2 = srcs[e + 2], s3 = srcs[e + 3];
    float w0 = nrm[e], w1 = nrm[e + 1], w2 = nrm[e + 2], w3 = nrm[e + 3];
    float4 x0 = *(const float4*)&tmp[(size_t)s0 * 128 + c4];
    float4 x1 = *(const float4*)&tmp[(size_t)s1 * 128 + c4];
    float4 x2 = *(const float4*)&tmp[(size_t)s2 * 128 + c4];
    float4 x3 = *(const float4*)&tmp[(size_t)s3 * 128 + c4];
    ax += w0 * x0.x + w1 * x1.x + w2 * x2.x + w3 * x3.x;
    ay += w0 * x0.y + w1 * x1.y + w2 * x2.y + w3 * x3.y;
    az += w0 * x0.z + w1 * x1.z + w2 * x2.z + w3 * x3.z;
    aw += w0 * x0.w + w1 * x1.w + w2 * x2.w + w3 * x3.w;
  }
  for (; e < e1; ++e) {
    int s = srcs[e];
    float w = nrm[e];
    float4 x0 = *(const float4*)&tmp[(size_t)s * 128 + c4];
    ax += w * x0.x; ay += w * x0.y; az += w * x0.z; aw += w * x0.w;
  }
  float4 bv = *(const float4*)&bias[c4];
  ax += bv.x; ay += bv.y; az += bv.z; aw += bv.w;
  if (RELU) {
    ax = fmaxf(ax, 0.f); ay = fmaxf(ay, 0.f);
    az = fmaxf(az, 0.f); aw = fmaxf(aw, 0.f);
  }
  float4 o = make_float4(ax, ay, az, aw);
  *(float4*)&out[(size_t)n * 128 + c4] = o;
}

// ---------- SYRK + row/col stats: partial-G stores (no G atomics) ----------

__global__ __launch_bounds__(256) void k_syrkstats(const float* __restrict__ h,
                                                   float* __restrict__ Gp,
                                                   float* __restrict__ colsum,
                                                   unsigned long long* __restrict__ packed,
                                                   int N, int rowsPer) {
  __shared__ float hs[8][132];
  __shared__ float csS[128];
  __shared__ unsigned long long pkS[8];
  int tid = threadIdx.x;
  int tx = tid & 15, ty = tid >> 4;
  int rr = tid >> 5, c4 = (tid & 31) * 4;
  float acc[8][8];
  #pragma unroll
  for (int i = 0; i < 8; i++)
    #pragma unroll
    for (int j = 0; j < 8; j++) acc[i][j] = 0.f;
  float ca0 = 0.f, ca1 = 0.f, ca2 = 0.f, ca3 = 0.f;
  unsigned long long best = 0;
  if (tid < 128) csS[tid] = 0.f;
  __syncthreads();

  int rstart = blockIdx.x * rowsPer;
  int rend = rstart + rowsPer;
  if (rend > N) rend = N;
  for (int rb = rstart; rb < rend; rb += 8) {
    int gr = rb + rr;
    float4 v = make_float4(0.f, 0.f, 0.f, 0.f);
    if (gr < rend) v = *(const float4*)&h[(size_t)gr * 128 + c4];
    __syncthreads();
    *(float4*)&hs[rr][c4] = v;
    float avx = fabsf(v.x), avy = fabsf(v.y), avz = fabsf(v.z), avw = fabsf(v.w);
    ca0 += avx; ca1 += avy; ca2 += avz; ca3 += avw;
    float rs = (avx + avy) + (avz + avw);
    rs = dpp_add<0xB1>(rs);
    rs = dpp_add<0x4E>(rs);
    rs = dpp_add<0x124>(rs);
    rs = dpp_add<0x128>(rs);
    rs = dpp_add<0x142>(rs);  // lanes 16-31 / 48-63 hold full 32-lane row sums
    if (gr < rend) {
      unsigned long long pk = ((unsigned long long)__float_as_uint(rs) << 32)
                            | (unsigned long long)(0xFFFFFFFFu - (unsigned)gr);
      if (pk > best) best = pk;
    }
    __syncthreads();
    #pragma unroll
    for (int r2 = 0; r2 < 8; r2++) {
      float4 a0 = *(const float4*)&hs[r2][ty * 8];
      float4 a1 = *(const float4*)&hs[r2][ty * 8 + 4];
      float4 b0 = *(const float4*)&hs[r2][tx * 8];
      float4 b1 = *(const float4*)&hs[r2][tx * 8 + 4];
      float a[8] = { a0.x,a0.y,a0.z,a0.w,a1.x,a1.y,a1.z,a1.w };
      float b[8] = { b0.x,b0.y,b0.z,b0.w,b1.x,b1.y,b1.z,b1.w };
      #pragma unroll
      for (int i = 0; i < 8; i++)
        #pragma unroll
        for (int j = 0; j < 8; j++) acc[i][j] += a[i] * b[j];
    }
  }
  if ((tid & 31) == 16) pkS[tid >> 5] = best;
  atomicAdd(&csS[c4 + 0], ca0);
  atomicAdd(&csS[c4 + 1], ca1);
  atomicAdd(&csS[c4 + 2], ca2);
  atomicAdd(&csS[c4 + 3], ca3);
  __syncthreads();
  if (tid == 0) {
    unsigned long long m = pkS[0];
    #pragma unroll
    for (int w = 1; w < 8; w++) if (pkS[w] > m) m = pkS[w];
    atomicMax(packed, m);
  }
  if (tid < 128) atomicAdd(&colsum[tid], csS[tid]);
  // partial-G store: private slice, pure coalesced stores
  float* Gs = Gp + (size_t)blockIdx.x * 16384;
  #pragma unroll
  for (int i = 0; i < 8; i++) {
    #pragma unroll
    for (int j4 = 0; j4 < 2; j4++) {
      float4 o = make_float4(acc[i][4*j4+0], acc[i][4*j4+1], acc[i][4*j4+2], acc[i][4*j4+3]);
      *(float4*)&Gs[(size_t)(ty * 8 + i) * 128 + tx * 8 + j4 * 4] = o;
    }
  }
}

// ------------------------------- megastats (R6 verbatim) -------------------

__global__ __launch_bounds__(512) void k_megastats4(const float* __restrict__ Gall,
                                                    const float* __restrict__ colall,
                                                    const float* __restrict__ hrowall,
                                                    const unsigned long long* __restrict__ pkd3,
                                                    const float* __restrict__ h3, int N,
                                                    float* __restrict__ outstats) {
  const int blk = blockIdx.x;
  const float* G = Gall + (size_t)blk * 16384;
  const float* colsum = colall + blk * 128;

  __shared__ __align__(16) float colk[128];
  __shared__ __align__(16) float wwF[256];    // ww[2][128] double buffer
  __shared__ __align__(16) float lamp[8];
  __shared__ float sigp[2];
  __shared__ float diag[128], offd[128];
  __shared__ float asS[128], b2S[128];
  __shared__ float loS[128], hiS[128];
  __shared__ float hiRow[128], gjS[128];
  __shared__ int cntS[512];
  __shared__ float redw[8];
  __shared__ float scal[16];
  __shared__ int ishared[4];

  const int tid = threadIdx.x;
  const int lane = tid & 63;
  const int wv = tid >> 6;     // wave 0..7
  const int q = tid >> 7;      // slice 0..3 (wave-pair)
  const int r = tid & 127;     // row
  const int cbase = q * 32;
  float Areg[32];

  #pragma unroll
  for (int cc = 0; cc < 32; cc++) {
    int c = cbase + cc;
    Areg[cc] = 0.5f * (G[(size_t)r * 128 + c] + G[(size_t)c * 128 + r]);
  }

  for (int solve = 0; solve < 2; solve++) {
    if (q == 0) colk[r] = (r == 0) ? 0.f : Areg[0];
    if (tid == 0) diag[0] = Areg[0];
    if (tid < 256) wwF[tid] = 0.f;
    if (q == 0) {
      float m2 = (r >= 1) ? Areg[0] * Areg[0] : 0.f;
      float s = wave_sum(m2);
      if (lane == 0) sigp[wv] = s;   // wv = 0,1
    }
    __syncthreads();

    for (int k = 0; k <= 125; k++) {
      const int kp1 = k + 1;
      float* wwc = &wwF[(k & 1) * 128];
      float* wwn = &wwF[(1 - (k & 1)) * 128];
      // ---- phase A ----
      float sig = sigp[0] + sigp[1];
      float xk1 = colk[kp1];
      float nx = sqrtf(sig);
      float alpha = (xk1 >= 0.f) ? -nx : nx;
      float vns = 2.0f * (sig - alpha * xk1);
      float rvn = (vns > 1e-35f) ? rsqrtf(vns) : 0.f;
      float narvn = -alpha * rvn;
      float ckr = colk[r];
      float vr = ckr * rvn + ((r == kp1) ? narvn : 0.f);
      const bool act = (cbase + 31 >= k);
      float4 cv[8];
      float p = 0.f;
      if (act) {
        const float4* cp = (const float4*)&colk[cbase];  // broadcast reads
        #pragma unroll
        for (int i = 0; i < 8; i++) cv[i] = cp[i];
        if (r >= k) {
          #pragma unroll
          for (int i = 0; i < 8; i++)
            p += Areg[4*i+0]*cv[i].x + Areg[4*i+1]*cv[i].y
               + Areg[4*i+2]*cv[i].z + Areg[4*i+3]*cv[i].w;
          int kl = kp1 - cbase;
          float akp1 = 0.f;
          if (kl >= 0 && kl < 32) {
            #pragma unroll
            for (int i = 0; i < 32; i++) if (i == kl) akp1 = Areg[i];
          }
          p = rvn * p + narvn * akp1;
          atomicAdd(&wwc[r], p);      // ds_add_f32, cross-wave combine
        }
      }
      float lp = vr * p;
      float ls = wave_sum(lp);
      if (lane == 0) lamp[wv] = ls;
      if (tid == 0) offd[k] = alpha;
      __syncthreads();

      // ---- phase B ----
      float4 l0 = *(const float4*)&lamp[0];
      float4 l1 = *(const float4*)&lamp[4];
      float lam = ((l0.x + l0.y) + (l0.z + l0.w)) + ((l1.x + l1.y) + (l1.z + l1.w));
      const int qo = kp1 >> 5;
      float nextc = 0.f;
      if (act && r >= k) {
        float wr = wwc[r];
        float qr = 2.0f * (wr - lam * vr);
        const int kl = kp1 - cbase;
        const float4* wp = (const float4*)&wwc[cbase];   // broadcast reads
        #pragma unroll
        for (int i = 0; i < 8; i++) {
          const int c0 = 4 * i;
          float4 wc = wp[i];
          float v0 = cv[i].x * rvn + ((c0 + 0 == kl) ? narvn : 0.f);
          float v1 = cv[i].y * rvn + ((c0 + 1 == kl) ? narvn : 0.f);
          float v2 = cv[i].z * rvn + ((c0 + 2 == kl) ? narvn : 0.f);
          float v3 = cv[i].w * rvn + ((c0 + 3 == kl) ? narvn : 0.f);
          float q0 = 2.f * (wc.x - lam * v0);
          float q1 = 2.f * (wc.y - lam * v1);
          float q2 = 2.f * (wc.z - lam * v2);
          float q3 = 2.f * (wc.w - lam * v3);
          float a0 = Areg[c0+0] - (vr * q0 + qr * v0); Areg[c0+0] = a0;
          float a1 = Areg[c0+1] - (vr * q1 + qr * v1); Areg[c0+1] = a1;
          float a2 = Areg[c0+2] - (vr * q2 + qr * v2); Areg[c0+2] = a2;
          float a3 = Areg[c0+3] - (vr * q3 + qr * v3); Areg[c0+3] = a3;
          if (c0 + 0 == kl) nextc = a0;
          if (c0 + 1 == kl) nextc = a1;
          if (c0 + 2 == kl) nextc = a2;
          if (c0 + 3 == kl) nextc = a3;
        }
      }
      if (q == qo && r >= k) colk[r] = (r <= kp1) ? 0.f : nextc;
      if (q == qo && r == kp1) diag[kp1] = nextc;
      if (q == qo) {
        float m2 = (r > kp1 && r >= k) ? nextc * nextc : 0.f;
        float s = wave_sum(m2);
        if (lane == 0) sigp[wv & 1] = s;
      }
      if (q == 1) wwn[r] = 0.f;   // zero next buffer
      __syncthreads();
    }
    if (tid == 0) offd[126] = colk[127];
    if (q == 3 && r == 127) diag[127] = Areg[31];
    __syncthreads();

    // ---- Gershgorin bound ----
    if (tid < 128) {
      float t = fabsf(diag[tid]);
      if (tid > 0) t += fabsf(offd[tid - 1]);
      if (tid < 127) t += fabsf(offd[tid]);
      #pragma unroll
      for (int m = 32; m >= 1; m >>= 1) t = fmaxf(t, __shfl_xor(t, m));
      if (lane == 0) redw[wv] = t;
    }
    __syncthreads();
    if (tid == 0) {
      float g = fmaxf(redw[0], redw[1]);
      if (!(g > 1e-30f)) g = 1.f;
      scal[3] = g; scal[5] = 1.0f / g;
    }
    __syncthreads();
    if (tid < 128) {
      float ginv = scal[5];
      asS[tid] = diag[tid] * ginv;
      float ob = (tid < 127) ? offd[tid] * ginv : 0.f;
      b2S[tid] = ob * ob;
      loS[tid] = -0.0625f;
      hiS[tid] = 1.03125f;
    }
    __syncthreads();

    // ---- multisection bisection (4 probes per eigenvalue, 12 rounds) ----
    for (int round = 0; round < 12; round++) {
      int kk = tid & 127;
      int t = tid >> 7;
      float l = loS[kk], h2v = hiS[kk];
      float sigma = l + (h2v - l) * 0.2f * (float)(t + 1);
      const float PIV = 1e-20f;
      float d = asS[0] - sigma;
      if (fabsf(d) < PIV) d = -PIV;
      int cnt = (d < 0.f) ? 1 : 0;
      for (int i = 1; i < 128; i++) {
        d = (asS[i] - sigma) - b2S[i - 1] * __builtin_amdgcn_rcpf(d);
        if (fabsf(d) < PIV) d = -PIV;
        cnt += (d < 0.f) ? 1 : 0;
      }
      cntS[tid] = cnt;
      __syncthreads();
      if (tid < 128) {
        int c0 = cntS[tid], c1 = cntS[tid + 128], c2 = cntS[tid + 256], c3 = cntS[tid + 384];
        float l2 = loS[tid], h2 = hiS[tid];
        float w = (h2 - l2) * 0.2f;
        int cross = 4;
        if (c0 > tid) cross = 0;
        else if (c1 > tid) cross = 1;
        else if (c2 > tid) cross = 2;
        else if (c3 > tid) cross = 3;
        loS[tid] = (cross == 0) ? l2 : l2 + w * (float)cross;
        hiS[tid] = (cross == 4) ? h2 : l2 + w * (float)(cross + 1);
      }
      __syncthreads();
    }
    // ---- sum sqrt eigenvalues ----
    if (tid < 128) {
      float lam2 = 0.5f * (loS[tid] + hiS[tid]);
      lam2 = fmaxf(lam2, 0.f) * scal[3];
      float s = sqrtf(lam2);
      #pragma unroll
      for (int m = 32; m >= 1; m >>= 1) s += __shfl_xor(s, m);
      if (lane == 0) redw[wv] = s;
    }
    __syncthreads();
    if (tid == 0) scal[4] = redw[0] + redw[1];
    __syncthreads();

    if (solve == 0) {
      if (tid < 128) {
        if (blk == 3) {
          unsigned long long pk = *pkd3;
          unsigned i = 0xFFFFFFFFu - (unsigned)(pk & 0xFFFFFFFFull);
          if (i >= (unsigned)N) i = 0;
          hiRow[tid] = h3[(size_t)i * 128 + tid];
        } else {
          hiRow[tid] = hrowall[blk * 128 + tid];
        }
      }
      __syncthreads();
      if (tid < 128) {
        float v = colsum[tid];
        int idx = tid;
        #pragma unroll
        for (int m = 32; m >= 1; m >>= 1) {
          float v2 = __shfl_xor(v, m);
          int i2 = __shfl_xor(idx, m);
          if (v2 > v || (v2 == v && i2 < idx)) { v = v2; idx = i2; }
        }
        if (lane == 0) { redw[wv] = v; ishared[wv] = idx; }
        float hv = hiRow[tid];
        float nh = hv * hv;
        #pragma unroll
        for (int m = 32; m >= 1; m >>= 1) nh += __shfl_xor(nh, m);
        if (lane == 0) redw[4 + wv] = nh;
      }
      __syncthreads();
      if (tid == 0) {
        float v0 = redw[0], v1 = redw[1];
        int j = (v1 > v0 || (v1 == v0 && ishared[1] < ishared[0])) ? ishared[1] : ishared[0];
        float nh2 = redw[4] + redw[5];
        float nu = scal[4];
        float Gjj = G[(size_t)j * 128 + j];
        float hij = hiRow[j];
        float sflip = (hij < 0.f) ? -1.f : 1.f;
        scal[6] = 1.0f / (nu * nu);
        scal[7] = sflip / (nu * sqrtf(Gjj) * sqrtf(nh2));
        scal[8] = 1.0f / nh2;
        ishared[2] = j;
      }
      __syncthreads();
      int j = ishared[2];
      if (tid < 128) gjS[tid] = 0.5f * (G[(size_t)tid * 128 + j] + G[(size_t)j * 128 + tid]);
      __syncthreads();
      float inv2 = scal[6], c1 = scal[7], c2 = scal[8];
      float gr_ = gjS[r], hr_ = hiRow[r];
      #pragma unroll
      for (int cc = 0; cc < 32; cc++) {
        int c = cbase + cc;
        float gsym = 0.5f * (G[(size_t)r * 128 + c] + G[(size_t)c * 128 + r]);
        Areg[cc] = gsym * inv2 - c1 * (gr_ * hiRow[c] + hr_ * gjS[c]) + c2 * hr_ * hiRow[c];
      }
      __syncthreads();
    }
  }
  if (tid == 0) outstats[blk] = scal[4];
}

// ------------------------------- host driver -------------------------------

extern "C" void kernel_launch(void* const* d_in, const int* in_sizes, int n_in,
                              void* d_out, int out_size, void* d_ws, size_t ws_size,
                              hipStream_t stream) {
  const float* x = (const float*)d_in[0];
  const int* edge = (const int*)d_in[1];
  const float* encW = (const float*)d_in[2];
  const float* encb = (const float*)d_in[3];
  const float* W0 = (const float*)d_in[4];
  const float* b0 = (const float*)d_in[5];
  const float* W1 = (const float*)d_in[6];
  const float* b1 = (const float*)d_in[7];
  const float* W2 = (const float*)d_in[8];
  const float* b2 = (const float*)d_in[9];

  const int N = in_sizes[0] / 128;
  const int E = in_sizes[1] / 2;
  const int* esrc = edge;
  const int* edst = edge + E;

  float* out = (float*)d_out;
  float* stats_out = out + (size_t)N * 128;

  char* ws = (char*)d_ws;
  size_t offTmp = 0;
  size_t offG = offTmp + (size_t)N * 128 * 4;
  size_t offCol = offG + 4 * 16384 * 4;
  size_t offPkd = offCol + 4 * 128 * 4;
  size_t offHrow = offPkd + 4 * 8;
  size_t offDeg = offHrow + 4 * 128 * 4;
  size_t offRp = offDeg + (size_t)N * 4;
  size_t offCur = offRp + (size_t)(N + 1) * 4;
  size_t offDinv = offCur + (size_t)N * 4;
  size_t offSrc = offDinv + (size_t)N * 4;
  size_t offNrm = offSrc + (size_t)E * 4;
  size_t offPart = offNrm + (size_t)E * 4;
  size_t offGp = offPart + 256;
  size_t total = offGp + (size_t)SYB * 16384 * 4;
  if (ws_size < total) return;

  float* tmp = (float*)(ws + offTmp);
  float* Gall = (float*)(ws + offG);
  float* colall = (float*)(ws + offCol);
  unsigned long long* pkdall = (unsigned long long*)(ws + offPkd);
  float* hrowall = (float*)(ws + offHrow);
  unsigned* deg = (unsigned*)(ws + offDeg);
  unsigned* rowptr = (unsigned*)(ws + offRp);
  unsigned* cursor = (unsigned*)(ws + offCur);
  float* dinv = (float*)(ws + offDinv);
  int* srcs = (int*)(ws + offSrc);
  float* nrm = (float*)(ws + offNrm);
  unsigned* part = (unsigned*)(ws + offPart);
  float* Gp = (float*)(ws + offGp);

  hipMemsetAsync(ws + offCol, 0, 4 * 128 * 4 + 4 * 8, stream);
  hipMemsetAsync(ws + offDeg, 0, (size_t)N * 4, stream);

  const int EB = (E + 255) / 256;
  const int NB8 = (N + 7) / 8;
  const int GB = (N + 127) / 128;
  const int SB = (N + 1023) / 1024;
  const int syrkRows = (N + SYB - 1) / SYB;

  k_deg<<<EB, 256, 0, stream>>>(edst, deg, E);
  k_scan1<<<SB, 1024, 0, stream>>>(deg, cursor, part, N);
  k_scan2<<<1, 64, 0, stream>>>(part, SB);
  k_scan3<<<SB, 1024, 0, stream>>>(deg, part, rowptr, cursor, dinv, N, SB);
  k_scatter<<<EB, 256, 0, stream>>>(esrc, edst, dinv, cursor, srcs, nrm, E);

  // encoder: h0 = x @ encW.T + encb  -> d_out
  k_gemm<<<GB, 256, 0, stream>>>(x, encW, encb, out, N, nullptr, nullptr, nullptr, nullptr);
  k_syrkstats<<<SYB, 256, 0, stream>>>(out, Gp, colall + 0 * 128, pkdall + 0, N, syrkRows);

  // layer 0 (gemm + folded extract(stat0) + folded reduce(G0))
  k_gemm<<<GB + 1 + 64, 256, 0, stream>>>(out, W0, nullptr, tmp, N,
                                          pkdall + 0, hrowall + 0 * 128, Gp, Gall + 0 * 16384);
  k_agg<true><<<NB8, 256, 0, stream>>>(tmp, rowptr, srcs, nrm, b0, out, N);
  k_syrkstats<<<SYB, 256, 0, stream>>>(out, Gp, colall + 1 * 128, pkdall + 1, N, syrkRows);

  // layer 1 (gemm + folded extract(stat1) + folded reduce(G1))
  k_gemm<<<GB + 1 + 64, 256, 0, stream>>>(out, W1, nullptr, tmp, N,
                                          pkdall + 1, hrowall + 1 * 128, Gp, Gall + 1 * 16384);
  k_agg<true><<<NB8, 256, 0, stream>>>(tmp, rowptr, srcs, nrm, b1, out, N);
  k_syrkstats<<<SYB, 256, 0, stream>>>(out, Gp, colall + 2 * 128, pkdall + 2, N, syrkRows);

  // layer 2 (gemm + folded extract(stat2) + folded reduce(G2); no relu)
  k_gemm<<<GB + 1 + 64, 256, 0, stream>>>(out, W2, nullptr, tmp, N,
                                          pkdall + 2, hrowall + 2 * 128, Gp, Gall + 2 * 16384);
  k_agg<false><<<NB8, 256, 0, stream>>>(tmp, rowptr, srcs, nrm, b2, out, N);
  k_syrkstats<<<SYB, 256, 0, stream>>>(out, Gp, colall + 3 * 128, pkdall + 3, N, syrkRows);
  k_greduce<<<64, 256, 0, stream>>>(Gp, Gall + 3 * 16384);

  // all four stats concurrently (stat 3 self-extracts from out = h3)
  k_megastats4<<<4, 512, 0, stream>>>(Gall, colall, hrowall, pkdall + 3, out, N, stats_out);
}

// Round 16
// 1179.231 us; speedup vs baseline: 3.6883x; 1.0012x over previous
//
#include <hip/hip_runtime.h>
#include <hip/hip_bf16.h>

// ---------------------------------------------------------------------------
// GCN (3-layer) + encoder + rank_diff stats, all fp32.
// R16: revert to R13 verbatim (known-good best: 1180us). The R14/R15
//      readlane experiment failed correctness twice with uninspectable
//      divergence semantics; R13's float4-broadcast mega (572-577us) is the
//      empirical optimum of the explored design space.
// ---------------------------------------------------------------------------

#define DIM 128
#define SYB 128   // syrk blocks == partial slices

// DPP helpers
template <int CTRL>
__device__ __forceinline__ float dpp_add(float v) {
  int x = __builtin_amdgcn_update_dpp(0, __float_as_int(v), CTRL, 0xF, 0xF, true);
  return v + __int_as_float(x);
}

// full 64-lane sum, result broadcast via readlane(63)
__device__ __forceinline__ float wave_sum(float v) {
  v = dpp_add<0xB1>(v);
  v = dpp_add<0x4E>(v);
  v = dpp_add<0x124>(v);
  v = dpp_add<0x128>(v);
  v = dpp_add<0x142>(v);
  v = dpp_add<0x143>(v);
  return __int_as_float(__builtin_amdgcn_readlane(__float_as_int(v), 63));
}

// ------------------------------- graph setup -------------------------------

__global__ void k_deg(const int* __restrict__ dst, unsigned* __restrict__ deg, int E) {
  int e = blockIdx.x * 256 + threadIdx.x;
  if (e < E) atomicAdd(&deg[dst[e]], 1u);
}

__global__ __launch_bounds__(1024) void k_scan1(const unsigned* __restrict__ deg,
                                                unsigned* __restrict__ loc,
                                                unsigned* __restrict__ part, int n) {
  __shared__ unsigned wtot[16];
  int tid = threadIdx.x, lane = tid & 63, wid = tid >> 6;
  int i = blockIdx.x * 1024 + tid;
  unsigned v = (i < n) ? deg[i] : 0u;
  unsigned s = v;
  #pragma unroll
  for (int d = 1; d < 64; d <<= 1) {
    unsigned t = __shfl_up(s, d);
    if (lane >= d) s += t;
  }
  if (lane == 63) wtot[wid] = s;
  __syncthreads();
  if (tid == 0) {
    unsigned acc = 0;
    #pragma unroll
    for (int w = 0; w < 16; w++) { unsigned t = wtot[w]; wtot[w] = acc; acc += t; }
    part[blockIdx.x] = acc;
  }
  __syncthreads();
  if (i < n) loc[i] = wtot[wid] + (s - v);
}

__global__ void k_scan2(unsigned* part, int nb) {
  int tid = threadIdx.x;  // 64 threads, nb <= 64
  unsigned v = (tid < nb) ? part[tid] : 0u;
  unsigned s = v;
  #pragma unroll
  for (int d = 1; d < 64; d <<= 1) {
    unsigned t = __shfl_up(s, d);
    if (tid >= d) s += t;
  }
  if (tid < nb) part[tid] = s - v;
  if (tid == 63) part[nb] = s;
}

__global__ __launch_bounds__(1024) void k_scan3(const unsigned* __restrict__ deg,
                                                const unsigned* __restrict__ part,
                                                unsigned* __restrict__ rowptr,
                                                unsigned* __restrict__ loc_cursor,
                                                float* __restrict__ dinv, int n, int nb) {
  int i = blockIdx.x * 1024 + threadIdx.x;
  if (i < n) {
    unsigned v = loc_cursor[i] + part[blockIdx.x];
    rowptr[i] = v;
    loc_cursor[i] = v;
    unsigned d = deg[i];
    dinv[i] = d ? 1.0f / sqrtf((float)d) : 0.0f;
  }
  if (i == 0) rowptr[n] = part[nb];
}

__global__ void k_scatter(const int* __restrict__ src, const int* __restrict__ dst,
                          const float* __restrict__ dinv, unsigned* __restrict__ cursor,
                          int* __restrict__ srcs, float* __restrict__ nrm, int E) {
  int e = blockIdx.x * 256 + threadIdx.x;
  if (e >= E) return;
  int s = src[e], d = dst[e];
  unsigned pos = atomicAdd(&cursor[d], 1u);
  srcs[pos] = s;
  nrm[pos] = dinv[s] * dinv[d];
}

// ------ GEMM: out = A @ W.T (+bias), + folded extract + folded G-reduce -----

__global__ __launch_bounds__(256, 2) void k_gemm(const float* __restrict__ A,
                                                 const float* __restrict__ W,
                                                 const float* __restrict__ bias,
                                                 float* __restrict__ out, int M,
                                                 const unsigned long long* __restrict__ packed,
                                                 float* __restrict__ hrow,
                                                 const float* __restrict__ Gp,
                                                 float* __restrict__ Gout) {
  const int tid = threadIdx.x;
  const int GBc = (M + 127) >> 7;
  const int bid = blockIdx.x;
  if (bid >= GBc) {
    if (bid == GBc) {
      if (packed != nullptr && tid < 128) {
        unsigned long long pk = *packed;
        unsigned i = 0xFFFFFFFFu - (unsigned)(pk & 0xFFFFFFFFull);
        if (i >= (unsigned)M) i = 0;
        hrow[tid] = A[(size_t)i * 128 + tid];
      }
    } else if (Gp != nullptr) {
      int idx = (bid - GBc - 1) * 256 + tid;   // 64 blocks x 256 = 16384
      float s = 0.f;
      #pragma unroll 8
      for (int p = 0; p < SYB; p++) s += Gp[(size_t)p * 16384 + idx];
      Gout[idx] = s;
    }
    return;
  }
  __shared__ float Hs[32][132];   // k-major: Hs[kk][row]
  __shared__ float Ws[32][132];   // k-major: Ws[kk][col]
  const int r0 = bid * 128;
  const int tx = tid & 15, ty = tid >> 4;
  const bool full = (r0 + 128 <= M);

  float acc[8][8];
  #pragma unroll
  for (int i = 0; i < 8; i++)
    #pragma unroll
    for (int j = 0; j < 8; j++) acc[i][j] = 0.f;

  #pragma unroll 1
  for (int k0 = 0; k0 < 128; k0 += 32) {
    #pragma unroll
    for (int i = 0; i < 4; i++) {
      int f4 = i * 256 + tid;
      int row = f4 >> 3, kq = f4 & 7;
      int gr = r0 + row;
      float4 v = make_float4(0.f, 0.f, 0.f, 0.f);
      if (full || gr < M) v = *(const float4*)&A[(size_t)gr * 128 + k0 + kq * 4];
      Hs[kq * 4 + 0][row] = v.x; Hs[kq * 4 + 1][row] = v.y;
      Hs[kq * 4 + 2][row] = v.z; Hs[kq * 4 + 3][row] = v.w;
    }
    #pragma unroll
    for (int i = 0; i < 4; i++) {
      int f4 = i * 256 + tid;
      int col = f4 >> 3, kq = f4 & 7;
      float4 v = *(const float4*)&W[(size_t)col * 128 + k0 + kq * 4];
      Ws[kq * 4 + 0][col] = v.x; Ws[kq * 4 + 1][col] = v.y;
      Ws[kq * 4 + 2][col] = v.z; Ws[kq * 4 + 3][col] = v.w;
    }
    __syncthreads();
    #pragma unroll 8
    for (int kk = 0; kk < 32; kk++) {
      float4 a0 = *(const float4*)&Hs[kk][ty * 8];
      float4 a1 = *(const float4*)&Hs[kk][ty * 8 + 4];
      float4 b0 = *(const float4*)&Ws[kk][tx * 8];
      float4 b1 = *(const float4*)&Ws[kk][tx * 8 + 4];
      float a[8] = { a0.x, a0.y, a0.z, a0.w, a1.x, a1.y, a1.z, a1.w };
      float b[8] = { b0.x, b0.y, b0.z, b0.w, b1.x, b1.y, b1.z, b1.w };
      #pragma unroll
      for (int i = 0; i < 8; i++)
        #pragma unroll
        for (int j = 0; j < 8; j++) acc[i][j] += a[i] * b[j];
    }
    __syncthreads();
  }

  float bb[8] = {0.f,0.f,0.f,0.f,0.f,0.f,0.f,0.f};
  if (bias) {
    float4 v0 = *(const float4*)&bias[tx * 8];
    float4 v1 = *(const float4*)&bias[tx * 8 + 4];
    bb[0]=v0.x; bb[1]=v0.y; bb[2]=v0.z; bb[3]=v0.w;
    bb[4]=v1.x; bb[5]=v1.y; bb[6]=v1.z; bb[7]=v1.w;
  }
  #pragma unroll
  for (int i = 0; i < 8; i++) {
    int gr = r0 + ty * 8 + i;
    if (full || gr < M) {
      float4 o0 = make_float4(acc[i][0]+bb[0], acc[i][1]+bb[1], acc[i][2]+bb[2], acc[i][3]+bb[3]);
      float4 o1 = make_float4(acc[i][4]+bb[4], acc[i][5]+bb[5], acc[i][6]+bb[6], acc[i][7]+bb[7]);
      *(float4*)&out[(size_t)gr * 128 + tx * 8] = o0;
      *(float4*)&out[(size_t)gr * 128 + tx * 8 + 4] = o1;
    }
  }
}

// standalone G-reduce (for the last layer's G, before megastats)
__global__ void k_greduce(const float* __restrict__ Gp, float* __restrict__ Gout) {
  int idx = blockIdx.x * 256 + threadIdx.x;
  float s = 0.f;
  #pragma unroll 8
  for (int p = 0; p < SYB; p++) s += Gp[(size_t)p * 16384 + idx];
  Gout[idx] = s;
}

// ------------- aggregation: 2 nodes/wave, float4, 4-edge unroll -------------

template <bool RELU>
__global__ __launch_bounds__(256) void k_agg(const float* __restrict__ tmp,
                                             const unsigned* __restrict__ rowptr,
                                             const int* __restrict__ srcs,
                                             const float* __restrict__ nrm,
                                             const float* __restrict__ bias,
                                             float* __restrict__ out, int N) {
  int tid = threadIdx.x;
  int wid = tid >> 6, lane = tid & 63;
  int half = lane >> 5;
  int c4 = (lane & 31) * 4;
  int n = blockIdx.x * 8 + wid * 2 + half;
  if (n >= N) return;
  unsigned e = rowptr[n], e1 = rowptr[n + 1];
  float ax = 0.f, ay = 0.f, az = 0.f, aw = 0.f;
  for (; e + 4 <= e1; e += 4) {
    int s0 = srcs[e], s1 = srcs[e + 1], s2 = srcs[e + 2], s3 = srcs[e + 3];
    float w0 = nrm[e], w1 = nrm[e + 1], w2 = nrm[e + 2], w3 = nrm[e + 3];
    float4 x0 = *(const float4*)&tmp[(size_t)s0 * 128 + c4];
    float4 x1 = *(const float4*)&tmp[(size_t)s1 * 128 + c4];
    float4 x2 = *(const float4*)&tmp[(size_t)s2 * 128 + c4];
    float4 x3 = *(const float4*)&tmp[(size_t)s3 * 128 + c4];
    ax += w0 * x0.x + w1 * x1.x + w2 * x2.x + w3 * x3.x;
    ay += w0 * x0.y + w1 * x1.y + w2 * x2.y + w3 * x3.y;
    az += w0 * x0.z + w1 * x1.z + w2 * x2.z + w3 * x3.z;
    aw += w0 * x0.w + w1 * x1.w + w2 * x2.w + w3 * x3.w;
  }
  for (; e < e1; ++e) {
    int s = srcs[e];
    float w = nrm[e];
    float4 x0 = *(const float4*)&tmp[(size_t)s * 128 + c4];
    ax += w * x0.x; ay += w * x0.y; az += w * x0.z; aw += w * x0.w;
  }
  float4 bv = *(const float4*)&bias[c4];
  ax += bv.x; ay += bv.y; az += bv.z; aw += bv.w;
  if (RELU) {
    ax = fmaxf(ax, 0.f); ay = fmaxf(ay, 0.f);
    az = fmaxf(az, 0.f); aw = fmaxf(aw, 0.f);
  }
  float4 o = make_float4(ax, ay, az, aw);
  *(float4*)&out[(size_t)n * 128 + c4] = o;
}

// ---------- SYRK + row/col stats: partial-G stores (no G atomics) ----------

__global__ __launch_bounds__(256) void k_syrkstats(const float* __restrict__ h,
                                                   float* __restrict__ Gp,
                                                   float* __restrict__ colsum,
                                                   unsigned long long* __restrict__ packed,
                                                   int N, int rowsPer) {
  __shared__ float hs[8][132];
  __shared__ float csS[128];
  __shared__ unsigned long long pkS[8];
  int tid = threadIdx.x;
  int tx = tid & 15, ty = tid >> 4;
  int rr = tid >> 5, c4 = (tid & 31) * 4;
  float acc[8][8];
  #pragma unroll
  for (int i = 0; i < 8; i++)
    #pragma unroll
    for (int j = 0; j < 8; j++) acc[i][j] = 0.f;
  float ca0 = 0.f, ca1 = 0.f, ca2 = 0.f, ca3 = 0.f;
  unsigned long long best = 0;
  if (tid < 128) csS[tid] = 0.f;
  __syncthreads();

  int rstart = blockIdx.x * rowsPer;
  int rend = rstart + rowsPer;
  if (rend > N) rend = N;
  for (int rb = rstart; rb < rend; rb += 8) {
    int gr = rb + rr;
    float4 v = make_float4(0.f, 0.f, 0.f, 0.f);
    if (gr < rend) v = *(const float4*)&h[(size_t)gr * 128 + c4];
    __syncthreads();
    *(float4*)&hs[rr][c4] = v;
    float avx = fabsf(v.x), avy = fabsf(v.y), avz = fabsf(v.z), avw = fabsf(v.w);
    ca0 += avx; ca1 += avy; ca2 += avz; ca3 += avw;
    float rs = (avx + avy) + (avz + avw);
    rs = dpp_add<0xB1>(rs);
    rs = dpp_add<0x4E>(rs);
    rs = dpp_add<0x124>(rs);
    rs = dpp_add<0x128>(rs);
    rs = dpp_add<0x142>(rs);  // lanes 16-31 / 48-63 hold full 32-lane row sums
    if (gr < rend) {
      unsigned long long pk = ((unsigned long long)__float_as_uint(rs) << 32)
                            | (unsigned long long)(0xFFFFFFFFu - (unsigned)gr);
      if (pk > best) best = pk;
    }
    __syncthreads();
    #pragma unroll
    for (int r2 = 0; r2 < 8; r2++) {
      float4 a0 = *(const float4*)&hs[r2][ty * 8];
      float4 a1 = *(const float4*)&hs[r2][ty * 8 + 4];
      float4 b0 = *(const float4*)&hs[r2][tx * 8];
      float4 b1 = *(const float4*)&hs[r2][tx * 8 + 4];
      float a[8] = { a0.x,a0.y,a0.z,a0.w,a1.x,a1.y,a1.z,a1.w };
      float b[8] = { b0.x,b0.y,b0.z,b0.w,b1.x,b1.y,b1.z,b1.w };
      #pragma unroll
      for (int i = 0; i < 8; i++)
        #pragma unroll
        for (int j = 0; j < 8; j++) acc[i][j] += a[i] * b[j];
    }
  }
  if ((tid & 31) == 16) pkS[tid >> 5] = best;
  atomicAdd(&csS[c4 + 0], ca0);
  atomicAdd(&csS[c4 + 1], ca1);
  atomicAdd(&csS[c4 + 2], ca2);
  atomicAdd(&csS[c4 + 3], ca3);
  __syncthreads();
  if (tid == 0) {
    unsigned long long m = pkS[0];
    #pragma unroll
    for (int w = 1; w < 8; w++) if (pkS[w] > m) m = pkS[w];
    atomicMax(packed, m);
  }
  if (tid < 128) atomicAdd(&colsum[tid], csS[tid]);
  // partial-G store: private slice, pure coalesced stores
  float* Gs = Gp + (size_t)blockIdx.x * 16384;
  #pragma unroll
  for (int i = 0; i < 8; i++) {
    #pragma unroll
    for (int j4 = 0; j4 < 2; j4++) {
      float4 o = make_float4(acc[i][4*j4+0], acc[i][4*j4+1], acc[i][4*j4+2], acc[i][4*j4+3]);
      *(float4*)&Gs[(size_t)(ty * 8 + i) * 128 + tx * 8 + j4 * 4] = o;
    }
  }
}

// ------------------------------- megastats (R6/R13 verbatim) ----------------
// One block per stat: 2x (tridiag + bisection) trace-sqrt on 128x128 Gram.
// q-major, 8 waves, 2 barriers/step, ds_add w-combine (the measured optimum).

__global__ __launch_bounds__(512) void k_megastats4(const float* __restrict__ Gall,
                                                    const float* __restrict__ colall,
                                                    const float* __restrict__ hrowall,
                                                    const unsigned long long* __restrict__ pkd3,
                                                    const float* __restrict__ h3, int N,
                                                    float* __restrict__ outstats) {
  const int blk = blockIdx.x;
  const float* G = Gall + (size_t)blk * 16384;
  const float* colsum = colall + blk * 128;

  __shared__ __align__(16) float colk[128];
  __shared__ __align__(16) float wwF[256];    // ww[2][128] double buffer
  __shared__ __align__(16) float lamp[8];
  __shared__ float sigp[2];
  __shared__ float diag[128], offd[128];
  __shared__ float asS[128], b2S[128];
  __shared__ float loS[128], hiS[128];
  __shared__ float hiRow[128], gjS[128];
  __shared__ int cntS[512];
  __shared__ float redw[8];
  __shared__ float scal[16];
  __shared__ int ishared[4];

  const int tid = threadIdx.x;
  const int lane = tid & 63;
  const int wv = tid >> 6;     // wave 0..7
  const int q = tid >> 7;      // slice 0..3 (wave-pair)
  const int r = tid & 127;     // row
  const int cbase = q * 32;
  float Areg[32];

  #pragma unroll
  for (int cc = 0; cc < 32; cc++) {
    int c = cbase + cc;
    Areg[cc] = 0.5f * (G[(size_t)r * 128 + c] + G[(size_t)c * 128 + r]);
  }

  for (int solve = 0; solve < 2; solve++) {
    if (q == 0) colk[r] = (r == 0) ? 0.f : Areg[0];
    if (tid == 0) diag[0] = Areg[0];
    if (tid < 256) wwF[tid] = 0.f;
    if (q == 0) {
      float m2 = (r >= 1) ? Areg[0] * Areg[0] : 0.f;
      float s = wave_sum(m2);
      if (lane == 0) sigp[wv] = s;   // wv = 0,1
    }
    __syncthreads();

    for (int k = 0; k <= 125; k++) {
      const int kp1 = k + 1;
      float* wwc = &wwF[(k & 1) * 128];
      float* wwn = &wwF[(1 - (k & 1)) * 128];
      // ---- phase A ----
      float sig = sigp[0] + sigp[1];
      float xk1 = colk[kp1];
      float nx = sqrtf(sig);
      float alpha = (xk1 >= 0.f) ? -nx : nx;
      float vns = 2.0f * (sig - alpha * xk1);
      float rvn = (vns > 1e-35f) ? rsqrtf(vns) : 0.f;
      float narvn = -alpha * rvn;
      float ckr = colk[r];
      float vr = ckr * rvn + ((r == kp1) ? narvn : 0.f);
      const bool act = (cbase + 31 >= k);
      float4 cv[8];
      float p = 0.f;
      if (act) {
        const float4* cp = (const float4*)&colk[cbase];  // broadcast reads
        #pragma unroll
        for (int i = 0; i < 8; i++) cv[i] = cp[i];
        if (r >= k) {
          #pragma unroll
          for (int i = 0; i < 8; i++)
            p += Areg[4*i+0]*cv[i].x + Areg[4*i+1]*cv[i].y
               + Areg[4*i+2]*cv[i].z + Areg[4*i+3]*cv[i].w;
          int kl = kp1 - cbase;
          float akp1 = 0.f;
          if (kl >= 0 && kl < 32) {
            #pragma unroll
            for (int i = 0; i < 32; i++) if (i == kl) akp1 = Areg[i];
          }
          p = rvn * p + narvn * akp1;
          atomicAdd(&wwc[r], p);      // ds_add_f32, cross-wave combine
        }
      }
      float lp = vr * p;
      float ls = wave_sum(lp);
      if (lane == 0) lamp[wv] = ls;
      if (tid == 0) offd[k] = alpha;
      __syncthreads();

      // ---- phase B ----
      float4 l0 = *(const float4*)&lamp[0];
      float4 l1 = *(const float4*)&lamp[4];
      float lam = ((l0.x + l0.y) + (l0.z + l0.w)) + ((l1.x + l1.y) + (l1.z + l1.w));
      const int qo = kp1 >> 5;
      float nextc = 0.f;
      if (act && r >= k) {
        float wr = wwc[r];
        float qr = 2.0f * (wr - lam * vr);
        const int kl = kp1 - cbase;
        const float4* wp = (const float4*)&wwc[cbase];   // broadcast reads
        #pragma unroll
        for (int i = 0; i < 8; i++) {
          const int c0 = 4 * i;
          float4 wc = wp[i];
          float v0 = cv[i].x * rvn + ((c0 + 0 == kl) ? narvn : 0.f);
          float v1 = cv[i].y * rvn + ((c0 + 1 == kl) ? narvn : 0.f);
          float v2 = cv[i].z * rvn + ((c0 + 2 == kl) ? narvn : 0.f);
          float v3 = cv[i].w * rvn + ((c0 + 3 == kl) ? narvn : 0.f);
          float q0 = 2.f * (wc.x - lam * v0);
          float q1 = 2.f * (wc.y - lam * v1);
          float q2 = 2.f * (wc.z - lam * v2);
          float q3 = 2.f * (wc.w - lam * v3);
          float a0 = Areg[c0+0] - (vr * q0 + qr * v0); Areg[c0+0] = a0;
          float a1 = Areg[c0+1] - (vr * q1 + qr * v1); Areg[c0+1] = a1;
          float a2 = Areg[c0+2] - (vr * q2 + qr * v2); Areg[c0+2] = a2;
          float a3 = Areg[c0+3] - (vr * q3 + qr * v3); Areg[c0+3] = a3;
          if (c0 + 0 == kl) nextc = a0;
          if (c0 + 1 == kl) nextc = a1;
          if (c0 + 2 == kl) nextc = a2;
          if (c0 + 3 == kl) nextc = a3;
        }
      }
      if (q == qo && r >= k) colk[r] = (r <= kp1) ? 0.f : nextc;
      if (q == qo && r == kp1) diag[kp1] = nextc;
      if (q == qo) {
        float m2 = (r > kp1 && r >= k) ? nextc * nextc : 0.f;
        float s = wave_sum(m2);
        if (lane == 0) sigp[wv & 1] = s;
      }
      if (q == 1) wwn[r] = 0.f;   // zero next buffer
      __syncthreads();
    }
    if (tid == 0) offd[126] = colk[127];
    if (q == 3 && r == 127) diag[127] = Areg[31];
    __syncthreads();

    // ---- Gershgorin bound ----
    if (tid < 128) {
      float t = fabsf(diag[tid]);
      if (tid > 0) t += fabsf(offd[tid - 1]);
      if (tid < 127) t += fabsf(offd[tid]);
      #pragma unroll
      for (int m = 32; m >= 1; m >>= 1) t = fmaxf(t, __shfl_xor(t, m));
      if (lane == 0) redw[wv] = t;
    }
    __syncthreads();
    if (tid == 0) {
      float g = fmaxf(redw[0], redw[1]);
      if (!(g > 1e-30f)) g = 1.f;
      scal[3] = g; scal[5] = 1.0f / g;
    }
    __syncthreads();
    if (tid < 128) {
      float ginv = scal[5];
      asS[tid] = diag[tid] * ginv;
      float ob = (tid < 127) ? offd[tid] * ginv : 0.f;
      b2S[tid] = ob * ob;
      loS[tid] = -0.0625f;
      hiS[tid] = 1.03125f;
    }
    __syncthreads();

    // ---- multisection bisection (4 probes per eigenvalue, 12 rounds) ----
    for (int round = 0; round < 12; round++) {
      int kk = tid & 127;
      int t = tid >> 7;
      float l = loS[kk], h2v = hiS[kk];
      float sigma = l + (h2v - l) * 0.2f * (float)(t + 1);
      const float PIV = 1e-20f;
      float d = asS[0] - sigma;
      if (fabsf(d) < PIV) d = -PIV;
      int cnt = (d < 0.f) ? 1 : 0;
      for (int i = 1; i < 128; i++) {
        d = (asS[i] - sigma) - b2S[i - 1] * __builtin_amdgcn_rcpf(d);
        if (fabsf(d) < PIV) d = -PIV;
        cnt += (d < 0.f) ? 1 : 0;
      }
      cntS[tid] = cnt;
      __syncthreads();
      if (tid < 128) {
        int c0 = cntS[tid], c1 = cntS[tid + 128], c2 = cntS[tid + 256], c3 = cntS[tid + 384];
        float l2 = loS[tid], h2 = hiS[tid];
        float w = (h2 - l2) * 0.2f;
        int cross = 4;
        if (c0 > tid) cross = 0;
        else if (c1 > tid) cross = 1;
        else if (c2 > tid) cross = 2;
        else if (c3 > tid) cross = 3;
        loS[tid] = (cross == 0) ? l2 : l2 + w * (float)cross;
        hiS[tid] = (cross == 4) ? h2 : l2 + w * (float)(cross + 1);
      }
      __syncthreads();
    }
    // ---- sum sqrt eigenvalues ----
    if (tid < 128) {
      float lam2 = 0.5f * (loS[tid] + hiS[tid]);
      lam2 = fmaxf(lam2, 0.f) * scal[3];
      float s = sqrtf(lam2);
      #pragma unroll
      for (int m = 32; m >= 1; m >>= 1) s += __shfl_xor(s, m);
      if (lane == 0) redw[wv] = s;
    }
    __syncthreads();
    if (tid == 0) scal[4] = redw[0] + redw[1];
    __syncthreads();

    if (solve == 0) {
      if (tid < 128) {
        if (blk == 3) {
          unsigned long long pk = *pkd3;
          unsigned i = 0xFFFFFFFFu - (unsigned)(pk & 0xFFFFFFFFull);
          if (i >= (unsigned)N) i = 0;
          hiRow[tid] = h3[(size_t)i * 128 + tid];
        } else {
          hiRow[tid] = hrowall[blk * 128 + tid];
        }
      }
      __syncthreads();
      if (tid < 128) {
        float v = colsum[tid];
        int idx = tid;
        #pragma unroll
        for (int m = 32; m >= 1; m >>= 1) {
          float v2 = __shfl_xor(v, m);
          int i2 = __shfl_xor(idx, m);
          if (v2 > v || (v2 == v && i2 < idx)) { v = v2; idx = i2; }
        }
        if (lane == 0) { redw[wv] = v; ishared[wv] = idx; }
        float hv = hiRow[tid];
        float nh = hv * hv;
        #pragma unroll
        for (int m = 32; m >= 1; m >>= 1) nh += __shfl_xor(nh, m);
        if (lane == 0) redw[4 + wv] = nh;
      }
      __syncthreads();
      if (tid == 0) {
        float v0 = redw[0], v1 = redw[1];
        int j = (v1 > v0 || (v1 == v0 && ishared[1] < ishared[0])) ? ishared[1] : ishared[0];
        float nh2 = redw[4] + redw[5];
        float nu = scal[4];
        float Gjj = G[(size_t)j * 128 + j];
        float hij = hiRow[j];
        float sflip = (hij < 0.f) ? -1.f : 1.f;
        scal[6] = 1.0f / (nu * nu);
        scal[7] = sflip / (nu * sqrtf(Gjj) * sqrtf(nh2));
        scal[8] = 1.0f / nh2;
        ishared[2] = j;
      }
      __syncthreads();
      int j = ishared[2];
      if (tid < 128) gjS[tid] = 0.5f * (G[(size_t)tid * 128 + j] + G[(size_t)j * 128 + tid]);
      __syncthreads();
      float inv2 = scal[6], c1 = scal[7], c2 = scal[8];
      float gr_ = gjS[r], hr_ = hiRow[r];
      #pragma unroll
      for (int cc = 0; cc < 32; cc++) {
        int c = cbase + cc;
        float gsym = 0.5f * (G[(size_t)r * 128 + c] + G[(size_t)c * 128 + r]);
        Areg[cc] = gsym * inv2 - c1 * (gr_ * hiRow[c] + hr_ * gjS[c]) + c2 * hr_ * hiRow[c];
      }
      __syncthreads();
    }
  }
  if (tid == 0) outstats[blk] = scal[4];
}

// ------------------------------- host driver -------------------------------

extern "C" void kernel_launch(void* const* d_in, const int* in_sizes, int n_in,
                              void* d_out, int out_size, void* d_ws, size_t ws_size,
                              hipStream_t stream) {
  const float* x = (const float*)d_in[0];
  const int* edge = (const int*)d_in[1];
  const float* encW = (const float*)d_in[2];
  const float* encb = (const float*)d_in[3];
  const float* W0 = (const float*)d_in[4];
  const float* b0 = (const float*)d_in[5];
  const float* W1 = (const float*)d_in[6];
  const float* b1 = (const float*)d_in[7];
  const float* W2 = (const float*)d_in[8];
  const float* b2 = (const float*)d_in[9];

  const int N = in_sizes[0] / 128;
  const int E = in_sizes[1] / 2;
  const int* esrc = edge;
  const int* edst = edge + E;

  float* out = (float*)d_out;
  float* stats_out = out + (size_t)N * 128;

  char* ws = (char*)d_ws;
  size_t offTmp = 0;
  size_t offG = offTmp + (size_t)N * 128 * 4;
  size_t offCol = offG + 4 * 16384 * 4;
  size_t offPkd = offCol + 4 * 128 * 4;
  size_t offHrow = offPkd + 4 * 8;
  size_t offDeg = offHrow + 4 * 128 * 4;
  size_t offRp = offDeg + (size_t)N * 4;
  size_t offCur = offRp + (size_t)(N + 1) * 4;
  size_t offDinv = offCur + (size_t)N * 4;
  size_t offSrc = offDinv + (size_t)N * 4;
  size_t offNrm = offSrc + (size_t)E * 4;
  size_t offPart = offNrm + (size_t)E * 4;
  size_t offGp = offPart + 256;
  size_t total = offGp + (size_t)SYB * 16384 * 4;
  if (ws_size < total) return;

  float* tmp = (float*)(ws + offTmp);
  float* Gall = (float*)(ws + offG);
  float* colall = (float*)(ws + offCol);
  unsigned long long* pkdall = (unsigned long long*)(ws + offPkd);
  float* hrowall = (float*)(ws + offHrow);
  unsigned* deg = (unsigned*)(ws + offDeg);
  unsigned* rowptr = (unsigned*)(ws + offRp);
  unsigned* cursor = (unsigned*)(ws + offCur);
  float* dinv = (float*)(ws + offDinv);
  int* srcs = (int*)(ws + offSrc);
  float* nrm = (float*)(ws + offNrm);
  unsigned* part = (unsigned*)(ws + offPart);
  float* Gp = (float*)(ws + offGp);

  hipMemsetAsync(ws + offCol, 0, 4 * 128 * 4 + 4 * 8, stream);
  hipMemsetAsync(ws + offDeg, 0, (size_t)N * 4, stream);

  const int EB = (E + 255) / 256;
  const int NB8 = (N + 7) / 8;
  const int GB = (N + 127) / 128;
  const int SB = (N + 1023) / 1024;
  const int syrkRows = (N + SYB - 1) / SYB;

  k_deg<<<EB, 256, 0, stream>>>(edst, deg, E);
  k_scan1<<<SB, 1024, 0, stream>>>(deg, cursor, part, N);
  k_scan2<<<1, 64, 0, stream>>>(part, SB);
  k_scan3<<<SB, 1024, 0, stream>>>(deg, part, rowptr, cursor, dinv, N, SB);
  k_scatter<<<EB, 256, 0, stream>>>(esrc, edst, dinv, cursor, srcs, nrm, E);

  // encoder: h0 = x @ encW.T + encb  -> d_out
  k_gemm<<<GB, 256, 0, stream>>>(x, encW, encb, out, N, nullptr, nullptr, nullptr, nullptr);
  k_syrkstats<<<SYB, 256, 0, stream>>>(out, Gp, colall + 0 * 128, pkdall + 0, N, syrkRows);

  // layer 0 (gemm + folded extract(stat0) + folded reduce(G0))
  k_gemm<<<GB + 1 + 64, 256, 0, stream>>>(out, W0, nullptr, tmp, N,
                                          pkdall + 0, hrowall + 0 * 128, Gp, Gall + 0 * 16384);
  k_agg<true><<<NB8, 256, 0, stream>>>(tmp, rowptr, srcs, nrm, b0, out, N);
  k_syrkstats<<<SYB, 256, 0, stream>>>(out, Gp, colall + 1 * 128, pkdall + 1, N, syrkRows);

  // layer 1 (gemm + folded extract(stat1) + folded reduce(G1))
  k_gemm<<<GB + 1 + 64, 256, 0, stream>>>(out, W1, nullptr, tmp, N,
                                          pkdall + 1, hrowall + 1 * 128, Gp, Gall + 1 * 16384);
  k_agg<true><<<NB8, 256, 0, stream>>>(tmp, rowptr, srcs, nrm, b1, out, N);
  k_syrkstats<<<SYB, 256, 0, stream>>>(out, Gp, colall + 2 * 128, pkdall + 2, N, syrkRows);

  // layer 2 (gemm + folded extract(stat2) + folded reduce(G2); no relu)
  k_gemm<<<GB + 1 + 64, 256, 0, stream>>>(out, W2, nullptr, tmp, N,
                                          pkdall + 2, hrowall + 2 * 128, Gp, Gall + 2 * 16384);
  k_agg<false><<<NB8, 256, 0, stream>>>(tmp, rowptr, srcs, nrm, b2, out, N);
  k_syrkstats<<<SYB, 256, 0, stream>>>(out, Gp, colall + 3 * 128, pkdall + 3, N, syrkRows);
  k_greduce<<<64, 256, 0, stream>>>(Gp, Gall + 3 * 16384);

  // all four stats concurrently (stat 3 self-extracts from out = h3)
  k_megastats4<<<4, 512, 0, stream>>>(Gall, colall, hrowall, pkdall + 3, out, N, stats_out);
}